// Round 11
// baseline (97.970 us; speedup 1.0000x reference)
//
#include <hip/hip_runtime.h>

#define NB 64
#define ZDIM 128
#define NCOEF 1025
#define NFR 128
#define COLS 131200          /* NCOEF*NFR */
#define WINSZ 2048
#define HALFW 1024
#define NSAMP 131072
#define IMPN 4096
#define NCHUNK 32            /* chunks of 4 spans */
#define NCK 31               /* checkpoints after frames 2,6,...,122 */

// workspace layout in floats
#define TF_OFF   0
#define TF_SZ    (NB*COLS)
#define TFT_OFF  (TF_OFF + TF_SZ)
#define TFT_SZ   (NB*NFR*NCOEF)
#define CUR_OFF  (TFT_OFF + TFT_SZ)
#define CUR_SZ   (NB*4*NCOEF*2)
#define CK_OFF   (CUR_OFF + CUR_SZ)
#define CK_SZ    (NCK*NB*NCOEF*2)
#define WINT_OFF (CK_OFF + CK_SZ)
#define WINT_SZ  (WINSZ)
#define TW_OFF   (WINT_OFF + WINT_SZ)
#define TW_SZ    (HALFW*2)
#define ZBF_OFF  (TW_OFF + TW_SZ)
#define ZBF_SZ   (NB*ZDIM/2)

// 2-bit XOR swizzle for the FFT plane: bits[3:2] ^= bits[5:4]
#define PHI(p) ((p) ^ ((((p) >> 4) & 3) << 2))

typedef short bf16x8 __attribute__((ext_vector_type(8)));
typedef float f32x4 __attribute__((ext_vector_type(4)));

__device__ __forceinline__ float2 cmul(float2 a, float2 b) {
  return make_float2(a.x * b.x - a.y * b.y, a.x * b.y + a.y * b.x);
}

// LDS-only workgroup barrier: drains LDS, leaves global loads in flight.
#define WGBAR()                                              \
  do {                                                       \
    asm volatile("s_waitcnt lgkmcnt(0)" ::: "memory");       \
    __builtin_amdgcn_s_barrier();                            \
    asm volatile("" ::: "memory");                           \
  } while (0)

__device__ __forceinline__ short f2bf(float f) {
  unsigned u = __builtin_bit_cast(unsigned, f);
  u += 0x7FFFu + ((u >> 16) & 1u);      // RNE
  return (short)(u >> 16);
}

__device__ __forceinline__ void gload_lds16(const float* g, float* l) {
  __builtin_amdgcn_global_load_lds(
      (const __attribute__((address_space(1))) unsigned int*)(const void*)g,
      (__attribute__((address_space(3))) unsigned int*)(void*)l, 16, 0, 0);
}

// ---------------------------------------------------------------- init tables (+ z->bf16)
__global__ __launch_bounds__(256) void init_tables(const float* __restrict__ z,
                                                   float* __restrict__ winT,
                                                   float2* __restrict__ twG,
                                                   short* __restrict__ zbf) {
  int i = blockIdx.x * 256 + threadIdx.x;   // grid 32*256 = 8192
  if (i < WINSZ) {
    winT[i] = 0.5f - 0.5f * cosf((float)(2.0 * 3.14159265358979323846 / 2048.0) * (float)i);
  }
  if (i < HALFW) {
    float ang = (float)(-2.0 * 3.14159265358979323846 / 2048.0) * (float)i;
    float sv, cv;
    sincosf(ang, &sv, &cv);
    twG[i] = make_float2(cv, sv);
  }
  if (i < NB * ZDIM) zbf[i] = f2bf(z[i]);
}

// ---------------------------------------------------------------- MFMA GEMM + squash
// W tile (128k x 128col, 64KB) staged via global_load_lds (coalesced 1KB/inst);
// B-frags built from LDS, A-frags from L2-hot zbf.
__global__ __launch_bounds__(256) void tf_gemm_mfma(const short* __restrict__ zbf,
                                                    const float* __restrict__ W,
                                                    const float* __restrict__ bias,
                                                    float* __restrict__ tf) {
  __shared__ float Wt[128 * 128];   // [kz][col], 64 KB
  int tid = threadIdx.x;
  int wave = tid >> 6, lane = tid & 63;
  int colb = blockIdx.x * 128;

  // stage: chunk cq covers rows {2cq, 2cq+1}, lane -> 16B
#pragma unroll
  for (int it = 0; it < 16; ++it) {
    int cq = wave * 16 + it;
    const float* src = W + (size_t)(2 * cq + (lane >> 5)) * COLS + colb + (lane & 31) * 4;
    gload_lds16(src, &Wt[cq * 256]);
  }

  int lr = lane & 15;
  int lk = (lane >> 4) * 8;
  int lq = (lane >> 4) * 4;
  int colw = colb + wave * 32;

  float bv[2];
#pragma unroll
  for (int n = 0; n < 2; ++n) bv[n] = bias[colw + 16 * n + lr];

  f32x4 acc[4][2];
#pragma unroll
  for (int m = 0; m < 4; ++m)
#pragma unroll
    for (int n = 0; n < 2; ++n)
      acc[m][n] = f32x4{bv[n], bv[n], bv[n], bv[n]};

  __syncthreads();   // stage complete (drains vmcnt)

#pragma unroll
  for (int s = 0; s < 4; ++s) {
    // A frags (zbf is 8KB, L2/L1-hot)
    bf16x8 afr[4];
#pragma unroll
    for (int m = 0; m < 4; ++m)
      afr[m] = *reinterpret_cast<const bf16x8*>(zbf + (16 * m + lr) * ZDIM + s * 32 + lk);
    // B frags from LDS
    bf16x8 bfr[2];
#pragma unroll
    for (int n = 0; n < 2; ++n) {
      const float* wp = &Wt[(s * 32 + lk) * 128 + wave * 32 + 16 * n + lr];
      bfr[n] = bf16x8{f2bf(wp[0 * 128]), f2bf(wp[1 * 128]), f2bf(wp[2 * 128]), f2bf(wp[3 * 128]),
                      f2bf(wp[4 * 128]), f2bf(wp[5 * 128]), f2bf(wp[6 * 128]), f2bf(wp[7 * 128])};
    }
#pragma unroll
    for (int m = 0; m < 4; ++m)
#pragma unroll
      for (int n = 0; n < 2; ++n)
        acc[m][n] = __builtin_amdgcn_mfma_f32_16x16x32_bf16(afr[m], bfr[n], acc[m][n], 0, 0, 0);
  }

  const float RESR = (1.0f - 0.02f) * 0.99f;
#pragma unroll
  for (int n = 0; n < 2; ++n) {
    int col = colw + 16 * n + lr;
#pragma unroll
    for (int m = 0; m < 4; ++m) {
      int rowb = 16 * m + lq;
#pragma unroll
      for (int r = 0; r < 4; ++r) {
        float x = acc[m][n][r];
        float sg = 1.0f / (1.0f + __expf(-x));
        tf[(size_t)(rowb + r) * COLS + col] = 0.02f + sg * RESR;
      }
    }
  }
}

// ---------------------------------------------------------------- fwd 2048 FFT (radix-2)
static __device__ __forceinline__ void wg_fft2048(float* ar, float* ai,
                                                  float* br, float* bi,
                                                  const float2* tw,
                                                  float** outr, float** outi) {
  float *xr = ar, *xi = ai, *yr = br, *yi = bi;
  int m = 1;
  for (int s = 0; s < 11; ++s) {
    __syncthreads();
#pragma unroll
    for (int it = 0; it < 4; ++it) {
      int t = (int)threadIdx.x + it * 256;
      int jm = t & ~(m - 1);
      float x0r = xr[t], x0i = xi[t];
      float x1r = xr[t + 1024], x1i = xi[t + 1024];
      float2 w = tw[jm];
      float sr = x0r + x1r, si = x0i + x1i;
      float dr = x0r - x1r, di = x0i - x1i;
      float pr = dr * w.x - di * w.y;
      float pi = dr * w.y + di * w.x;
      yr[t + jm] = sr;      yi[t + jm] = si;
      yr[t + jm + m] = pr;  yi[t + jm + m] = pi;
    }
    float* t0 = xr; xr = yr; yr = t0;
    float* t1 = xi; xi = yi; yi = t1;
    m <<= 1;
  }
  __syncthreads();
  *outr = xr; *outi = xi;
}

__global__ __launch_bounds__(256) void fwd_fft_kernel(const float* __restrict__ imp,
                                                      const float* __restrict__ winT,
                                                      const float2* __restrict__ twG,
                                                      float2* __restrict__ cur) {
  __shared__ float b0r[WINSZ], b0i[WINSZ], b1r[WINSZ], b1i[WINSZ];
  __shared__ float2 tw[HALFW];
  int wg = blockIdx.x;
  int b = wg >> 2, f = wg & 3;
  int tid = threadIdx.x;

  for (int i = tid; i < HALFW; i += 256) tw[i] = twG[i];
  for (int w = tid; w < WINSZ; w += 256) {
    int s = f * HALFW + w;
    float v = (s < IMPN) ? imp[(size_t)b * IMPN + s] * winT[w] : 0.0f;
    b0r[w] = v;
    b0i[w] = 0.0f;
  }
  float *rr, *ri;
  wg_fft2048(b0r, b0i, b1r, b1i, tw, &rr, &ri);
  for (int k = tid; k < NCOEF; k += 256)
    cur[(size_t)wg * NCOEF + k] = make_float2(rr[k], ri[k]);
}

// ---------------------------------------------------------------- recurrence checkpoints + tf transpose
__global__ __launch_bounds__(256) void recur_ck_t(const float* __restrict__ tf,
                                                  const float2* __restrict__ cur,
                                                  float2* __restrict__ ckp,
                                                  float* __restrict__ tft) {
  int id = blockIdx.x * 256 + threadIdx.x;
  if (id >= NB * NCOEF) return;
  int b = id / NCOEF;
  int k = id - b * NCOEF;

  float g = 3.14159265358979323846f * (float)k / 1024.0f;
  float sg, cg;
  sincosf(g, &sg, &cg);
  bool herm = (k == 0) || (k == HALFW);

  const float4* tf4 = (const float4*)(tf + (size_t)b * COLS + (size_t)k * NFR);
  const float2* curb = cur + (size_t)b * 4 * NCOEF + k;
  float* tftb = tft + (size_t)b * NFR * NCOEF + k;

  float pre = 0.0f, pim = 0.0f;
  for (int f4 = 0; f4 < 32; ++f4) {
    float4 tv = tf4[f4];
    float tfs[4] = {tv.x, tv.y, tv.z, tv.w};
#pragma unroll
    for (int u = 0; u < 4; ++u) {
      int f = 4 * f4 + u;
      tftb[(size_t)f * NCOEF] = tfs[u];       // coalesced transpose write
      if (f < 124) {
        float tfv = tfs[u];
        float cr = 0.0f, ci = 0.0f;
        if (f < 4) {
          float2 cv = curb[(size_t)f * NCOEF];
          cr = cv.x; ci = cv.y;
        }
        float ire = herm ? 0.0f : pim;
        float rre = fmaf(pre, cg, ire * sg);
        float rim = -fmaf(pre, sg, ire * cg);
        float sre = (cr + rre) * tfv;
        float sim = (ci + rim) * tfv;
        if ((f & 3) == 2)
          ckp[(size_t)((f - 2) >> 2) * NB * NCOEF + (size_t)b * NCOEF + k] = make_float2(sre, sim);
        pre = sre; pim = sim;
      }
    }
  }
}

// ---------------------------------------------------------------- fused recur + irfft + OLA
// Register DIF radix-4; P/Q planes; 3 LDS-only barriers/frame. Twiddle powers
// recomputed in-loop (asm tie prevents re-hoisting) to keep VGPR <= 64.
__global__ __launch_bounds__(256) void fused_resyn(const float* __restrict__ tft,
                                                   const float2* __restrict__ cur,
                                                   const float2* __restrict__ ckp,
                                                   const float* __restrict__ winT,
                                                   const float2* __restrict__ twG,
                                                   float* __restrict__ out) {
  __shared__ float2 P[1024];   // X plane (mirror source)
  __shared__ float2 Q[1024];   // butterfly work plane

  int bidx = blockIdx.x;
  int b = bidx >> 5, c = bidx & 31;
  int t = threadIdx.x;

  // ---- recurrence slots: k = t + 256*i (i<4); thread 0 also owns k=1024
  float pre[5], pim[5], cgv[5], sgv[5];
#pragma unroll
  for (int i = 0; i < 5; ++i) {
    if (i == 4) { cgv[4] = -1.0f; sgv[4] = 0.0f; }
    else {
      float2 tv = twG[t + 256 * i];
      cgv[i] = tv.x; sgv[i] = -tv.y;       // cos/sin(pi*k/1024)
    }
    pre[i] = 0.0f; pim[i] = 0.0f;
  }
  if (c > 0) {
    const float2* ck = ckp + ((size_t)(c - 1) * NB + b) * NCOEF;
#pragma unroll
    for (int i = 0; i < 5; ++i) {
      if (i == 4 && t != 0) continue;
      int k = (i == 4) ? 1024 : t + 256 * i;
      float2 v = ck[k];
      pre[i] = v.x; pim[i] = v.y;
    }
  }

  // ---- base twiddles only (squares/cubes recomputed per frame)
  float2 w1a = twG[2 * t];
  float2 w2a = twG[8 * (t & 63)];
  float2 w3a = twG[32 * (t & 15)];
  float2 w4a = twG[128 * (t & 3)];
  float2 twp0 = twG[t];

  // ---- extract constants (digit-reversed output positions)
  int mb = (t >> 6) + ((t >> 4) & 3) * 4 + ((t >> 2) & 3) * 16 + (t & 3) * 64;
  const float2* win2 = (const float2*)winT;
  float2 wv0 = win2[mb], wv1 = win2[mb + 256], wv2 = win2[mb + 512], wv3 = win2[mb + 768];

  // ---- LDS address constants (swizzled)
  int X0 = PHI(t);
  int B2 = 256 * (t >> 6) + ((t & 63) ^ (((t >> 4) & 3) << 2));
  int b3h = 64 * (t >> 4), i3 = t & 15;
  int b4h = 16 * (t >> 2), i4 = t & 3, c4 = (t >> 2) & 3;
  int p5 = b4h + 4 * ((t & 3) ^ c4);
  int pm0 = PHI((1024 - t) & 1023);
  int pm1 = PHI((1024 - (t + 256)) & 1023);
  int pm2 = PHI((1024 - (t + 512)) & 1023);
  int pm3 = PHI((1024 - (t + 768)) & 1023);

  const float* tftb = tft + (size_t)b * NFR * NCOEF;
  const float2* curb = cur + (size_t)b * 4 * NCOEF;
  const float Cs = 0.5f / 1024.0f;

  int fs = (c == 0) ? 0 : 4 * c - 1;
  int fe = 4 * c + 3;
  float carE0 = 0.0f, carO0 = 0.0f, carE1 = 0.0f, carO1 = 0.0f;

  // ---- tf prefetch for frame fs
  float ntf[5];
  {
    const float* tfr = tftb + (size_t)fs * NCOEF;
#pragma unroll
    for (int i = 0; i < 4; ++i) ntf[i] = tfr[t + 256 * i];
    ntf[4] = (t == 0) ? tfr[1024] : 0.0f;
  }

#define KEEP(x) asm volatile("" : "+v"(x))

  for (int f = fs; f <= fe; ++f) {
    // tie base twiddles so derived powers are recomputed (not hoisted)
    KEEP(w1a.x); KEEP(w1a.y); KEEP(w2a.x); KEEP(w2a.y);
    KEEP(w3a.x); KEEP(w3a.y); KEEP(w4a.x); KEEP(w4a.y);
    KEEP(twp0.x); KEEP(twp0.y);

    float ctf[5];
#pragma unroll
    for (int i = 0; i < 5; ++i) ctf[i] = ntf[i];

    // ---- issue next frame's tf loads (hide under this frame's FFT)
    if (f < fe) {
      const float* tfr = tftb + (size_t)(f + 1) * NCOEF;
#pragma unroll
      for (int i = 0; i < 4; ++i) ntf[i] = tfr[t + 256 * i];
      ntf[4] = (t == 0) ? tfr[1024] : 0.0f;
    }

    // ---- advance recurrence (registers)
    float S[5], I[5];
#pragma unroll
    for (int i = 0; i < 5; ++i) {
      if (i == 4 && t != 0) { S[4] = 0.0f; I[4] = 0.0f; continue; }
      float cr = 0.0f, ci = 0.0f;
      if (f < 4) {
        int k = (i == 4) ? 1024 : t + 256 * i;
        float2 cv = curb[(size_t)f * NCOEF + k];
        cr = cv.x; ci = cv.y;
      }
      float rre = fmaf(pre[i], cgv[i], pim[i] * sgv[i]);
      float rim = -fmaf(pre[i], sgv[i], pim[i] * cgv[i]);
      S[i] = (cr + rre) * ctf[i];
      I[i] = (ci + rim) * ctf[i];
      pre[i] = S[i]; pim[i] = I[i];
    }

    // ---- X into P
#pragma unroll
    for (int i = 0; i < 4; ++i)
      P[X0 + 256 * i] = make_float2(S[i], I[i]);
    WGBAR();                               // (alpha) X visible

    // ---- pack Z (own X from regs; mirror from P) + stage-1 butterfly
    // twp1 = twp0*e^{-i pi/4}; twp2 = twp0*e^{-i pi/2}; twp3 = twp1*e^{-i pi/2}
    const float R2 = 0.70710678118654752f;
    float2 twp1 = cmul(twp0, make_float2(R2, -R2));
    float2 twp2 = make_float2(twp0.y, -twp0.x);
    float2 twp3 = make_float2(twp1.y, -twp1.x);
    float2 Z[4];
    {
      float2 xm[4];
      xm[0] = (t == 0) ? make_float2(S[4], 0.0f) : P[pm0];
      xm[1] = P[pm1]; xm[2] = P[pm2]; xm[3] = P[pm3];
      float2 twp[4] = {twp0, twp1, twp2, twp3};
#pragma unroll
      for (int i = 0; i < 4; ++i) {
        float xjr = S[i], xji = I[i];
        float cc = twp[i].x, sn = -twp[i].y;   // e^{+2pi i j/2048}
        float Xer = Cs * (xjr + xm[i].x), Xei = Cs * (xji - xm[i].y);
        float Xpr = Cs * (xjr - xm[i].x), Xpi = Cs * (xji + xm[i].y);
        float Xor_ = Xpr * cc - Xpi * sn;
        float Xoi_ = Xpr * sn + Xpi * cc;
        Z[i] = make_float2(Xer - Xoi_, -(Xei + Xor_));
      }
    }
    float2 y0, y1, y2, y3;
    {
      float2 w1b = cmul(w1a, w1a);
      float2 w1c = cmul(w1b, w1a);
      float2 A = make_float2(Z[0].x + Z[2].x, Z[0].y + Z[2].y);
      float2 Bv = make_float2(Z[0].x - Z[2].x, Z[0].y - Z[2].y);
      float2 Cv = make_float2(Z[1].x + Z[3].x, Z[1].y + Z[3].y);
      float2 D = make_float2(Z[1].x - Z[3].x, Z[1].y - Z[3].y);
      y0 = make_float2(A.x + Cv.x, A.y + Cv.y);
      y1 = cmul(make_float2(Bv.x + D.y, Bv.y - D.x), w1a);
      y2 = cmul(make_float2(A.x - Cv.x, A.y - Cv.y), w1b);
      y3 = cmul(make_float2(Bv.x - D.y, Bv.y + D.x), w1c);
    }
    WGBAR();                               // (beta) prev stage-5 reads of Q done
    Q[X0]       = y0;
    Q[X0 + 256] = y1;
    Q[X0 + 512] = y2;
    Q[X0 + 768] = y3;
    WGBAR();                               // (gamma) y visible across waves

    // ---- stage 2 (wave-local, N=256)
    float2 u0 = Q[B2], u1 = Q[B2 + 64], u2 = Q[B2 + 128], u3 = Q[B2 + 192];
    {
      float2 w2b = cmul(w2a, w2a);
      float2 w2c = cmul(w2b, w2a);
      float2 A = make_float2(u0.x + u2.x, u0.y + u2.y);
      float2 Bv = make_float2(u0.x - u2.x, u0.y - u2.y);
      float2 Cv = make_float2(u1.x + u3.x, u1.y + u3.y);
      float2 D = make_float2(u1.x - u3.x, u1.y - u3.y);
      Q[B2]       = make_float2(A.x + Cv.x, A.y + Cv.y);
      Q[B2 + 64]  = cmul(make_float2(Bv.x + D.y, Bv.y - D.x), w2a);
      Q[B2 + 128] = cmul(make_float2(A.x - Cv.x, A.y - Cv.y), w2b);
      Q[B2 + 192] = cmul(make_float2(Bv.x - D.y, Bv.y + D.x), w2c);
    }
    asm volatile("s_waitcnt lgkmcnt(0)" ::: "memory");

    // ---- stage 3 (N=64)
    u0 = Q[b3h + i3];
    u1 = Q[b3h + 16 + (i3 ^ 4)];
    u2 = Q[b3h + 32 + (i3 ^ 8)];
    u3 = Q[b3h + 48 + (i3 ^ 12)];
    {
      float2 w3b = cmul(w3a, w3a);
      float2 w3c = cmul(w3b, w3a);
      float2 A = make_float2(u0.x + u2.x, u0.y + u2.y);
      float2 Bv = make_float2(u0.x - u2.x, u0.y - u2.y);
      float2 Cv = make_float2(u1.x + u3.x, u1.y + u3.y);
      float2 D = make_float2(u1.x - u3.x, u1.y - u3.y);
      Q[b3h + i3]             = make_float2(A.x + Cv.x, A.y + Cv.y);
      Q[b3h + 16 + (i3 ^ 4)]  = cmul(make_float2(Bv.x + D.y, Bv.y - D.x), w3a);
      Q[b3h + 32 + (i3 ^ 8)]  = cmul(make_float2(A.x - Cv.x, A.y - Cv.y), w3b);
      Q[b3h + 48 + (i3 ^ 12)] = cmul(make_float2(Bv.x - D.y, Bv.y + D.x), w3c);
    }
    asm volatile("s_waitcnt lgkmcnt(0)" ::: "memory");

    // ---- stage 4 (N=16)
    u0 = Q[b4h + 4 * (0 ^ c4) + i4];
    u1 = Q[b4h + 4 * (1 ^ c4) + i4];
    u2 = Q[b4h + 4 * (2 ^ c4) + i4];
    u3 = Q[b4h + 4 * (3 ^ c4) + i4];
    {
      float2 w4b = cmul(w4a, w4a);
      float2 w4c = cmul(w4b, w4a);
      float2 A = make_float2(u0.x + u2.x, u0.y + u2.y);
      float2 Bv = make_float2(u0.x - u2.x, u0.y - u2.y);
      float2 Cv = make_float2(u1.x + u3.x, u1.y + u3.y);
      float2 D = make_float2(u1.x - u3.x, u1.y - u3.y);
      Q[b4h + 4 * (0 ^ c4) + i4] = make_float2(A.x + Cv.x, A.y + Cv.y);
      Q[b4h + 4 * (1 ^ c4) + i4] = cmul(make_float2(Bv.x + D.y, Bv.y - D.x), w4a);
      Q[b4h + 4 * (2 ^ c4) + i4] = cmul(make_float2(A.x - Cv.x, A.y - Cv.y), w4b);
      Q[b4h + 4 * (3 ^ c4) + i4] = cmul(make_float2(Bv.x - D.y, Bv.y + D.x), w4c);
    }
    asm volatile("s_waitcnt lgkmcnt(0)" ::: "memory");

    // ---- stage 5 (N=4) -> regs
    float4 q01 = *reinterpret_cast<const float4*>(&Q[p5]);
    float4 q23 = *reinterpret_cast<const float4*>(&Q[p5 + 2]);
    float2 z0, z1, z2, z3;
    {
      float2 a = make_float2(q01.x, q01.y), bq = make_float2(q01.z, q01.w);
      float2 cq = make_float2(q23.x, q23.y), d = make_float2(q23.z, q23.w);
      float2 A = make_float2(a.x + cq.x, a.y + cq.y);
      float2 Bv = make_float2(a.x - cq.x, a.y - cq.y);
      float2 Cv = make_float2(bq.x + d.x, bq.y + d.y);
      float2 D = make_float2(bq.x - d.x, bq.y - d.y);
      z0 = make_float2(A.x + Cv.x, A.y + Cv.y);
      z1 = make_float2(Bv.x + D.y, Bv.y - D.x);
      z2 = make_float2(A.x - Cv.x, A.y - Cv.y);
      z3 = make_float2(Bv.x - D.y, Bv.y + D.x);
    }

    // ---- extract: x[2m]=Re z[m], x[2m+1]=-Im z[m]; m = mb + 256q
    float e0 = z0.x * wv0.x, o0 = -z0.y * wv0.y;
    float e1 = z1.x * wv1.x, o1 = -z1.y * wv1.y;
    float e2 = z2.x * wv2.x, o2 = -z2.y * wv2.y;
    float e3 = z3.x * wv3.x, o3 = -z3.y * wv3.y;
    if (f >= 4 * c) {
      float2* ob2 = (float2*)(out + (size_t)b * NSAMP + (size_t)f * 1024);
      ob2[mb]       = make_float2(e0 + carE0, o0 + carO0);
      ob2[mb + 256] = make_float2(e1 + carE1, o1 + carO1);
    }
    carE0 = e2; carO0 = o2;
    carE1 = e3; carO1 = o3;
  }
#undef KEEP
}

// ---------------------------------------------------------------- launch
extern "C" void kernel_launch(void* const* d_in, const int* in_sizes, int n_in,
                              void* d_out, int out_size, void* d_ws, size_t ws_size,
                              hipStream_t stream) {
  const float* z    = (const float*)d_in[0];
  const float* imp  = (const float*)d_in[1];
  const float* W    = (const float*)d_in[2];
  const float* bias = (const float*)d_in[3];

  float* ws = (float*)d_ws;
  float*  tf   = ws + TF_OFF;
  float*  tft  = ws + TFT_OFF;
  float2* cur  = (float2*)(ws + CUR_OFF);
  float2* ckp  = (float2*)(ws + CK_OFF);
  float*  winT = ws + WINT_OFF;
  float2* twG  = (float2*)(ws + TW_OFF);
  short*  zbf  = (short*)(ws + ZBF_OFF);
  float*  out  = (float*)d_out;

  init_tables<<<32, 256, 0, stream>>>(z, winT, twG, zbf);
  tf_gemm_mfma<<<COLS / 128, 256, 0, stream>>>(zbf, W, bias, tf);
  fwd_fft_kernel<<<NB * 4, 256, 0, stream>>>(imp, winT, twG, cur);
  recur_ck_t<<<(NB * NCOEF + 255) / 256, 256, 0, stream>>>(tf, cur, ckp, tft);
  fused_resyn<<<NB * NCHUNK, 256, 0, stream>>>(tft, cur, ckp, winT, twG, out);
}

// Round 12
// 89.086 us; speedup vs baseline: 1.0997x; 1.0997x over previous
//
#include <hip/hip_runtime.h>

#define NB 64
#define ZDIM 128
#define NCOEF 1025
#define NFR 128
#define COLS 131200          /* NCOEF*NFR */
#define WINSZ 2048
#define HALFW 1024
#define NSAMP 131072
#define IMPN 4096
#define NCHUNK 32            /* chunks of 4 spans */
#define NCK 31               /* checkpoints after frames 2,6,...,122 */

// workspace layout in floats
#define TF_OFF   0
#define TF_SZ    (NB*COLS)
#define TFT_OFF  (TF_OFF + TF_SZ)
#define TFT_SZ   (NB*NFR*NCOEF)
#define CUR_OFF  (TFT_OFF + TFT_SZ)
#define CUR_SZ   (NB*4*NCOEF*2)
#define CK_OFF   (CUR_OFF + CUR_SZ)
#define CK_SZ    (NCK*NB*NCOEF*2)
#define WINT_OFF (CK_OFF + CK_SZ)
#define WINT_SZ  (WINSZ)
#define TW_OFF   (WINT_OFF + WINT_SZ)
#define TW_SZ    (HALFW*2)
#define ZBF_OFF  (TW_OFF + TW_SZ)
#define ZBF_SZ   (NB*ZDIM/2)

// 2-bit XOR swizzle for the FFT plane: bits[3:2] ^= bits[5:4]
#define PHI(p) ((p) ^ ((((p) >> 4) & 3) << 2))

typedef short bf16x8 __attribute__((ext_vector_type(8)));
typedef float f32x4 __attribute__((ext_vector_type(4)));

__device__ __forceinline__ float2 cmul(float2 a, float2 b) {
  return make_float2(a.x * b.x - a.y * b.y, a.x * b.y + a.y * b.x);
}

// LDS-only workgroup barrier: drains LDS, leaves global loads in flight.
#define WGBAR()                                              \
  do {                                                       \
    asm volatile("s_waitcnt lgkmcnt(0)" ::: "memory");       \
    __builtin_amdgcn_s_barrier();                            \
    asm volatile("" ::: "memory");                           \
  } while (0)

__device__ __forceinline__ short f2bf(float f) {
  unsigned u = __builtin_bit_cast(unsigned, f);
  u += 0x7FFFu + ((u >> 16) & 1u);      // RNE
  return (short)(u >> 16);
}

__device__ __forceinline__ void gload_lds16(const float* g, float* l) {
  __builtin_amdgcn_global_load_lds(
      (const __attribute__((address_space(1))) unsigned int*)(const void*)g,
      (__attribute__((address_space(3))) unsigned int*)(void*)l, 16, 0, 0);
}

// ---------------------------------------------------------------- init tables (+ z->bf16)
__global__ __launch_bounds__(256) void init_tables(const float* __restrict__ z,
                                                   float* __restrict__ winT,
                                                   float2* __restrict__ twG,
                                                   short* __restrict__ zbf) {
  int i = blockIdx.x * 256 + threadIdx.x;   // grid 32*256 = 8192
  if (i < WINSZ) {
    winT[i] = 0.5f - 0.5f * cosf((float)(2.0 * 3.14159265358979323846 / 2048.0) * (float)i);
  }
  if (i < HALFW) {
    float ang = (float)(-2.0 * 3.14159265358979323846 / 2048.0) * (float)i;
    float sv, cv;
    sincosf(ang, &sv, &cv);
    twG[i] = make_float2(cv, sv);
  }
  if (i < NB * ZDIM) zbf[i] = f2bf(z[i]);
}

// ---------------------------------------------------------------- MFMA GEMM + squash
// 32-col tiles (grid 4100): W tile 128x32 f32 = 16KB LDS -> 8-10 blocks/CU
// co-resident, deep cross-block fetch overlap. Wave w owns rows 16w..16w+15.
__global__ __launch_bounds__(256) void tf_gemm_mfma(const short* __restrict__ zbf,
                                                    const float* __restrict__ W,
                                                    const float* __restrict__ bias,
                                                    float* __restrict__ tf) {
  __shared__ float Wt[128 * 32];   // [k][col], 16 KB
  int tid = threadIdx.x;
  int wave = tid >> 6, lane = tid & 63;
  int colb = blockIdx.x * 32;

  // stage: 1024 x 16B chunks; chunk ci -> row ci>>3, col4 ci&7. 4 per thread.
#pragma unroll
  for (int it = 0; it < 4; ++it) {
    int ci = tid + it * 256;
    const float* src = W + (size_t)(ci >> 3) * COLS + colb + (ci & 7) * 4;
    gload_lds16(src, &Wt[ci * 4]);
  }

  int lr = lane & 15;
  int lk = (lane >> 4) * 8;
  int lq = (lane >> 4) * 4;

  float bv[2];
#pragma unroll
  for (int n = 0; n < 2; ++n) bv[n] = bias[colb + 16 * n + lr];

  f32x4 acc[2];
#pragma unroll
  for (int n = 0; n < 2; ++n)
    acc[n] = f32x4{bv[n], bv[n], bv[n], bv[n]};

  // A frags: rows 16*wave + lr (L2-hot zbf)
  bf16x8 afr[4];
#pragma unroll
  for (int s = 0; s < 4; ++s)
    afr[s] = *reinterpret_cast<const bf16x8*>(zbf + (16 * wave + lr) * ZDIM + s * 32 + lk);

  __syncthreads();   // stage complete

#pragma unroll
  for (int s = 0; s < 4; ++s) {
    bf16x8 bfr[2];
#pragma unroll
    for (int n = 0; n < 2; ++n) {
      const float* wp = &Wt[(s * 32 + lk) * 32 + 16 * n + lr];
      bfr[n] = bf16x8{f2bf(wp[0 * 32]), f2bf(wp[1 * 32]), f2bf(wp[2 * 32]), f2bf(wp[3 * 32]),
                      f2bf(wp[4 * 32]), f2bf(wp[5 * 32]), f2bf(wp[6 * 32]), f2bf(wp[7 * 32])};
    }
#pragma unroll
    for (int n = 0; n < 2; ++n)
      acc[n] = __builtin_amdgcn_mfma_f32_16x16x32_bf16(afr[s], bfr[n], acc[n], 0, 0, 0);
  }

  const float RESR = (1.0f - 0.02f) * 0.99f;
#pragma unroll
  for (int n = 0; n < 2; ++n) {
    int col = colb + 16 * n + lr;
#pragma unroll
    for (int r = 0; r < 4; ++r) {
      int row = 16 * wave + lq + r;
      float x = acc[n][r];
      float sg = 1.0f / (1.0f + __expf(-x));
      tf[(size_t)row * COLS + col] = 0.02f + sg * RESR;
    }
  }
}

// ---------------------------------------------------------------- fwd 2048 FFT (radix-2)
static __device__ __forceinline__ void wg_fft2048(float* ar, float* ai,
                                                  float* br, float* bi,
                                                  const float2* tw,
                                                  float** outr, float** outi) {
  float *xr = ar, *xi = ai, *yr = br, *yi = bi;
  int m = 1;
  for (int s = 0; s < 11; ++s) {
    __syncthreads();
#pragma unroll
    for (int it = 0; it < 4; ++it) {
      int t = (int)threadIdx.x + it * 256;
      int jm = t & ~(m - 1);
      float x0r = xr[t], x0i = xi[t];
      float x1r = xr[t + 1024], x1i = xi[t + 1024];
      float2 w = tw[jm];
      float sr = x0r + x1r, si = x0i + x1i;
      float dr = x0r - x1r, di = x0i - x1i;
      float pr = dr * w.x - di * w.y;
      float pi = dr * w.y + di * w.x;
      yr[t + jm] = sr;      yi[t + jm] = si;
      yr[t + jm + m] = pr;  yi[t + jm + m] = pi;
    }
    float* t0 = xr; xr = yr; yr = t0;
    float* t1 = xi; xi = yi; yi = t1;
    m <<= 1;
  }
  __syncthreads();
  *outr = xr; *outi = xi;
}

__global__ __launch_bounds__(256) void fwd_fft_kernel(const float* __restrict__ imp,
                                                      const float* __restrict__ winT,
                                                      const float2* __restrict__ twG,
                                                      float2* __restrict__ cur) {
  __shared__ float b0r[WINSZ], b0i[WINSZ], b1r[WINSZ], b1i[WINSZ];
  __shared__ float2 tw[HALFW];
  int wg = blockIdx.x;
  int b = wg >> 2, f = wg & 3;
  int tid = threadIdx.x;

  for (int i = tid; i < HALFW; i += 256) tw[i] = twG[i];
  for (int w = tid; w < WINSZ; w += 256) {
    int s = f * HALFW + w;
    float v = (s < IMPN) ? imp[(size_t)b * IMPN + s] * winT[w] : 0.0f;
    b0r[w] = v;
    b0i[w] = 0.0f;
  }
  float *rr, *ri;
  wg_fft2048(b0r, b0i, b1r, b1i, tw, &rr, &ri);
  for (int k = tid; k < NCOEF; k += 256)
    cur[(size_t)wg * NCOEF + k] = make_float2(rr[k], ri[k]);
}

// ---------------------------------------------------------------- recurrence checkpoints + tf transpose
__global__ __launch_bounds__(256) void recur_ck_t(const float* __restrict__ tf,
                                                  const float2* __restrict__ cur,
                                                  float2* __restrict__ ckp,
                                                  float* __restrict__ tft) {
  int id = blockIdx.x * 256 + threadIdx.x;
  if (id >= NB * NCOEF) return;
  int b = id / NCOEF;
  int k = id - b * NCOEF;

  float g = 3.14159265358979323846f * (float)k / 1024.0f;
  float sg, cg;
  sincosf(g, &sg, &cg);
  bool herm = (k == 0) || (k == HALFW);

  const float4* tf4 = (const float4*)(tf + (size_t)b * COLS + (size_t)k * NFR);
  const float2* curb = cur + (size_t)b * 4 * NCOEF + k;
  float* tftb = tft + (size_t)b * NFR * NCOEF + k;

  float pre = 0.0f, pim = 0.0f;
  for (int f4 = 0; f4 < 32; ++f4) {
    float4 tv = tf4[f4];
    float tfs[4] = {tv.x, tv.y, tv.z, tv.w};
#pragma unroll
    for (int u = 0; u < 4; ++u) {
      int f = 4 * f4 + u;
      tftb[(size_t)f * NCOEF] = tfs[u];       // coalesced transpose write
      if (f < 124) {
        float tfv = tfs[u];
        float cr = 0.0f, ci = 0.0f;
        if (f < 4) {
          float2 cv = curb[(size_t)f * NCOEF];
          cr = cv.x; ci = cv.y;
        }
        float ire = herm ? 0.0f : pim;
        float rre = fmaf(pre, cg, ire * sg);
        float rim = -fmaf(pre, sg, ire * cg);
        float sre = (cr + rre) * tfv;
        float sim = (ci + rim) * tfv;
        if ((f & 3) == 2)
          ckp[(size_t)((f - 2) >> 2) * NB * NCOEF + (size_t)b * NCOEF + k] = make_float2(sre, sim);
        pre = sre; pim = sim;
      }
    }
  }
}

// ---------------------------------------------------------------- fused recur + irfft + OLA
// Register DIF radix-4; P/Q planes; 3 LDS-only barriers/frame. Twiddle powers
// recomputed in-loop (asm tie prevents re-hoisting) to keep VGPR <= 64.
__global__ __launch_bounds__(256) void fused_resyn(const float* __restrict__ tft,
                                                   const float2* __restrict__ cur,
                                                   const float2* __restrict__ ckp,
                                                   const float* __restrict__ winT,
                                                   const float2* __restrict__ twG,
                                                   float* __restrict__ out) {
  __shared__ float2 P[1024];   // X plane (mirror source)
  __shared__ float2 Q[1024];   // butterfly work plane

  int bidx = blockIdx.x;
  int b = bidx >> 5, c = bidx & 31;
  int t = threadIdx.x;

  // ---- recurrence slots: k = t + 256*i (i<4); thread 0 also owns k=1024
  float pre[5], pim[5], cgv[5], sgv[5];
#pragma unroll
  for (int i = 0; i < 5; ++i) {
    if (i == 4) { cgv[4] = -1.0f; sgv[4] = 0.0f; }
    else {
      float2 tv = twG[t + 256 * i];
      cgv[i] = tv.x; sgv[i] = -tv.y;       // cos/sin(pi*k/1024)
    }
    pre[i] = 0.0f; pim[i] = 0.0f;
  }
  if (c > 0) {
    const float2* ck = ckp + ((size_t)(c - 1) * NB + b) * NCOEF;
#pragma unroll
    for (int i = 0; i < 5; ++i) {
      if (i == 4 && t != 0) continue;
      int k = (i == 4) ? 1024 : t + 256 * i;
      float2 v = ck[k];
      pre[i] = v.x; pim[i] = v.y;
    }
  }

  // ---- base twiddles only (squares/cubes recomputed per frame)
  float2 w1a = twG[2 * t];
  float2 w2a = twG[8 * (t & 63)];
  float2 w3a = twG[32 * (t & 15)];
  float2 w4a = twG[128 * (t & 3)];
  float2 twp0 = twG[t];

  // ---- extract constants (digit-reversed output positions)
  int mb = (t >> 6) + ((t >> 4) & 3) * 4 + ((t >> 2) & 3) * 16 + (t & 3) * 64;
  const float2* win2 = (const float2*)winT;
  float2 wv0 = win2[mb], wv1 = win2[mb + 256], wv2 = win2[mb + 512], wv3 = win2[mb + 768];

  // ---- LDS address constants (swizzled)
  int X0 = PHI(t);
  int B2 = 256 * (t >> 6) + ((t & 63) ^ (((t >> 4) & 3) << 2));
  int b3h = 64 * (t >> 4), i3 = t & 15;
  int b4h = 16 * (t >> 2), i4 = t & 3, c4 = (t >> 2) & 3;
  int p5 = b4h + 4 * ((t & 3) ^ c4);
  int pm0 = PHI((1024 - t) & 1023);
  int pm1 = PHI((1024 - (t + 256)) & 1023);
  int pm2 = PHI((1024 - (t + 512)) & 1023);
  int pm3 = PHI((1024 - (t + 768)) & 1023);

  const float* tftb = tft + (size_t)b * NFR * NCOEF;
  const float2* curb = cur + (size_t)b * 4 * NCOEF;
  const float Cs = 0.5f / 1024.0f;

  int fs = (c == 0) ? 0 : 4 * c - 1;
  int fe = 4 * c + 3;
  float carE0 = 0.0f, carO0 = 0.0f, carE1 = 0.0f, carO1 = 0.0f;

  // ---- tf prefetch for frame fs
  float ntf[5];
  {
    const float* tfr = tftb + (size_t)fs * NCOEF;
#pragma unroll
    for (int i = 0; i < 4; ++i) ntf[i] = tfr[t + 256 * i];
    ntf[4] = (t == 0) ? tfr[1024] : 0.0f;
  }

#define KEEP(x) asm volatile("" : "+v"(x))

  for (int f = fs; f <= fe; ++f) {
    // tie base twiddles so derived powers are recomputed (not hoisted)
    KEEP(w1a.x); KEEP(w1a.y); KEEP(w2a.x); KEEP(w2a.y);
    KEEP(w3a.x); KEEP(w3a.y); KEEP(w4a.x); KEEP(w4a.y);
    KEEP(twp0.x); KEEP(twp0.y);

    float ctf[5];
#pragma unroll
    for (int i = 0; i < 5; ++i) ctf[i] = ntf[i];

    // ---- issue next frame's tf loads (hide under this frame's FFT)
    if (f < fe) {
      const float* tfr = tftb + (size_t)(f + 1) * NCOEF;
#pragma unroll
      for (int i = 0; i < 4; ++i) ntf[i] = tfr[t + 256 * i];
      ntf[4] = (t == 0) ? tfr[1024] : 0.0f;
    }

    // ---- advance recurrence (registers)
    float S[5], I[5];
#pragma unroll
    for (int i = 0; i < 5; ++i) {
      if (i == 4 && t != 0) { S[4] = 0.0f; I[4] = 0.0f; continue; }
      float cr = 0.0f, ci = 0.0f;
      if (f < 4) {
        int k = (i == 4) ? 1024 : t + 256 * i;
        float2 cv = curb[(size_t)f * NCOEF + k];
        cr = cv.x; ci = cv.y;
      }
      float rre = fmaf(pre[i], cgv[i], pim[i] * sgv[i]);
      float rim = -fmaf(pre[i], sgv[i], pim[i] * cgv[i]);
      S[i] = (cr + rre) * ctf[i];
      I[i] = (ci + rim) * ctf[i];
      pre[i] = S[i]; pim[i] = I[i];
    }

    // ---- X into P
#pragma unroll
    for (int i = 0; i < 4; ++i)
      P[X0 + 256 * i] = make_float2(S[i], I[i]);
    WGBAR();                               // (alpha) X visible

    // ---- pack Z (own X from regs; mirror from P) + stage-1 butterfly
    const float R2 = 0.70710678118654752f;
    float2 twp1 = cmul(twp0, make_float2(R2, -R2));
    float2 twp2 = make_float2(twp0.y, -twp0.x);
    float2 twp3 = make_float2(twp1.y, -twp1.x);
    float2 Z[4];
    {
      float2 xm[4];
      xm[0] = (t == 0) ? make_float2(S[4], 0.0f) : P[pm0];
      xm[1] = P[pm1]; xm[2] = P[pm2]; xm[3] = P[pm3];
      float2 twp[4] = {twp0, twp1, twp2, twp3};
#pragma unroll
      for (int i = 0; i < 4; ++i) {
        float xjr = S[i], xji = I[i];
        float cc = twp[i].x, sn = -twp[i].y;   // e^{+2pi i j/2048}
        float Xer = Cs * (xjr + xm[i].x), Xei = Cs * (xji - xm[i].y);
        float Xpr = Cs * (xjr - xm[i].x), Xpi = Cs * (xji + xm[i].y);
        float Xor_ = Xpr * cc - Xpi * sn;
        float Xoi_ = Xpr * sn + Xpi * cc;
        Z[i] = make_float2(Xer - Xoi_, -(Xei + Xor_));
      }
    }
    float2 y0, y1, y2, y3;
    {
      float2 w1b = cmul(w1a, w1a);
      float2 w1c = cmul(w1b, w1a);
      float2 A = make_float2(Z[0].x + Z[2].x, Z[0].y + Z[2].y);
      float2 Bv = make_float2(Z[0].x - Z[2].x, Z[0].y - Z[2].y);
      float2 Cv = make_float2(Z[1].x + Z[3].x, Z[1].y + Z[3].y);
      float2 D = make_float2(Z[1].x - Z[3].x, Z[1].y - Z[3].y);
      y0 = make_float2(A.x + Cv.x, A.y + Cv.y);
      y1 = cmul(make_float2(Bv.x + D.y, Bv.y - D.x), w1a);
      y2 = cmul(make_float2(A.x - Cv.x, A.y - Cv.y), w1b);
      y3 = cmul(make_float2(Bv.x - D.y, Bv.y + D.x), w1c);
    }
    WGBAR();                               // (beta) prev stage-5 reads of Q done
    Q[X0]       = y0;
    Q[X0 + 256] = y1;
    Q[X0 + 512] = y2;
    Q[X0 + 768] = y3;
    WGBAR();                               // (gamma) y visible across waves

    // ---- stage 2 (wave-local, N=256)
    float2 u0 = Q[B2], u1 = Q[B2 + 64], u2 = Q[B2 + 128], u3 = Q[B2 + 192];
    {
      float2 w2b = cmul(w2a, w2a);
      float2 w2c = cmul(w2b, w2a);
      float2 A = make_float2(u0.x + u2.x, u0.y + u2.y);
      float2 Bv = make_float2(u0.x - u2.x, u0.y - u2.y);
      float2 Cv = make_float2(u1.x + u3.x, u1.y + u3.y);
      float2 D = make_float2(u1.x - u3.x, u1.y - u3.y);
      Q[B2]       = make_float2(A.x + Cv.x, A.y + Cv.y);
      Q[B2 + 64]  = cmul(make_float2(Bv.x + D.y, Bv.y - D.x), w2a);
      Q[B2 + 128] = cmul(make_float2(A.x - Cv.x, A.y - Cv.y), w2b);
      Q[B2 + 192] = cmul(make_float2(Bv.x - D.y, Bv.y + D.x), w2c);
    }
    asm volatile("s_waitcnt lgkmcnt(0)" ::: "memory");

    // ---- stage 3 (N=64)
    u0 = Q[b3h + i3];
    u1 = Q[b3h + 16 + (i3 ^ 4)];
    u2 = Q[b3h + 32 + (i3 ^ 8)];
    u3 = Q[b3h + 48 + (i3 ^ 12)];
    {
      float2 w3b = cmul(w3a, w3a);
      float2 w3c = cmul(w3b, w3a);
      float2 A = make_float2(u0.x + u2.x, u0.y + u2.y);
      float2 Bv = make_float2(u0.x - u2.x, u0.y - u2.y);
      float2 Cv = make_float2(u1.x + u3.x, u1.y + u3.y);
      float2 D = make_float2(u1.x - u3.x, u1.y - u3.y);
      Q[b3h + i3]             = make_float2(A.x + Cv.x, A.y + Cv.y);
      Q[b3h + 16 + (i3 ^ 4)]  = cmul(make_float2(Bv.x + D.y, Bv.y - D.x), w3a);
      Q[b3h + 32 + (i3 ^ 8)]  = cmul(make_float2(A.x - Cv.x, A.y - Cv.y), w3b);
      Q[b3h + 48 + (i3 ^ 12)] = cmul(make_float2(Bv.x - D.y, Bv.y + D.x), w3c);
    }
    asm volatile("s_waitcnt lgkmcnt(0)" ::: "memory");

    // ---- stage 4 (N=16)
    u0 = Q[b4h + 4 * (0 ^ c4) + i4];
    u1 = Q[b4h + 4 * (1 ^ c4) + i4];
    u2 = Q[b4h + 4 * (2 ^ c4) + i4];
    u3 = Q[b4h + 4 * (3 ^ c4) + i4];
    {
      float2 w4b = cmul(w4a, w4a);
      float2 w4c = cmul(w4b, w4a);
      float2 A = make_float2(u0.x + u2.x, u0.y + u2.y);
      float2 Bv = make_float2(u0.x - u2.x, u0.y - u2.y);
      float2 Cv = make_float2(u1.x + u3.x, u1.y + u3.y);
      float2 D = make_float2(u1.x - u3.x, u1.y - u3.y);
      Q[b4h + 4 * (0 ^ c4) + i4] = make_float2(A.x + Cv.x, A.y + Cv.y);
      Q[b4h + 4 * (1 ^ c4) + i4] = cmul(make_float2(Bv.x + D.y, Bv.y - D.x), w4a);
      Q[b4h + 4 * (2 ^ c4) + i4] = cmul(make_float2(A.x - Cv.x, A.y - Cv.y), w4b);
      Q[b4h + 4 * (3 ^ c4) + i4] = cmul(make_float2(Bv.x - D.y, Bv.y + D.x), w4c);
    }
    asm volatile("s_waitcnt lgkmcnt(0)" ::: "memory");

    // ---- stage 5 (N=4) -> regs
    float4 q01 = *reinterpret_cast<const float4*>(&Q[p5]);
    float4 q23 = *reinterpret_cast<const float4*>(&Q[p5 + 2]);
    float2 z0, z1, z2, z3;
    {
      float2 a = make_float2(q01.x, q01.y), bq = make_float2(q01.z, q01.w);
      float2 cq = make_float2(q23.x, q23.y), d = make_float2(q23.z, q23.w);
      float2 A = make_float2(a.x + cq.x, a.y + cq.y);
      float2 Bv = make_float2(a.x - cq.x, a.y - cq.y);
      float2 Cv = make_float2(bq.x + d.x, bq.y + d.y);
      float2 D = make_float2(bq.x - d.x, bq.y - d.y);
      z0 = make_float2(A.x + Cv.x, A.y + Cv.y);
      z1 = make_float2(Bv.x + D.y, Bv.y - D.x);
      z2 = make_float2(A.x - Cv.x, A.y - Cv.y);
      z3 = make_float2(Bv.x - D.y, Bv.y + D.x);
    }

    // ---- extract: x[2m]=Re z[m], x[2m+1]=-Im z[m]; m = mb + 256q
    float e0 = z0.x * wv0.x, o0 = -z0.y * wv0.y;
    float e1 = z1.x * wv1.x, o1 = -z1.y * wv1.y;
    float e2 = z2.x * wv2.x, o2 = -z2.y * wv2.y;
    float e3 = z3.x * wv3.x, o3 = -z3.y * wv3.y;
    if (f >= 4 * c) {
      float2* ob2 = (float2*)(out + (size_t)b * NSAMP + (size_t)f * 1024);
      ob2[mb]       = make_float2(e0 + carE0, o0 + carO0);
      ob2[mb + 256] = make_float2(e1 + carE1, o1 + carO1);
    }
    carE0 = e2; carO0 = o2;
    carE1 = e3; carO1 = o3;
  }
#undef KEEP
}

// ---------------------------------------------------------------- launch
extern "C" void kernel_launch(void* const* d_in, const int* in_sizes, int n_in,
                              void* d_out, int out_size, void* d_ws, size_t ws_size,
                              hipStream_t stream) {
  const float* z    = (const float*)d_in[0];
  const float* imp  = (const float*)d_in[1];
  const float* W    = (const float*)d_in[2];
  const float* bias = (const float*)d_in[3];

  float* ws = (float*)d_ws;
  float*  tf   = ws + TF_OFF;
  float*  tft  = ws + TFT_OFF;
  float2* cur  = (float2*)(ws + CUR_OFF);
  float2* ckp  = (float2*)(ws + CK_OFF);
  float*  winT = ws + WINT_OFF;
  float2* twG  = (float2*)(ws + TW_OFF);
  short*  zbf  = (short*)(ws + ZBF_OFF);
  float*  out  = (float*)d_out;

  init_tables<<<32, 256, 0, stream>>>(z, winT, twG, zbf);
  tf_gemm_mfma<<<COLS / 32, 256, 0, stream>>>(zbf, W, bias, tf);
  fwd_fft_kernel<<<NB * 4, 256, 0, stream>>>(imp, winT, twG, cur);
  recur_ck_t<<<(NB * NCOEF + 255) / 256, 256, 0, stream>>>(tf, cur, ckp, tft);
  fused_resyn<<<NB * NCHUNK, 256, 0, stream>>>(tft, cur, ckp, winT, twG, out);
}

// Round 13
// 85.820 us; speedup vs baseline: 1.1416x; 1.0381x over previous
//
#include <hip/hip_runtime.h>

#define NB 64
#define ZDIM 128
#define NCOEF 1025
#define NFR 128
#define COLS 131200          /* NCOEF*NFR */
#define WINSZ 2048
#define HALFW 1024
#define NSAMP 131072
#define IMPN 4096
#define NCHUNK 32            /* chunks of 4 spans */
#define NCK 31               /* checkpoints after frames 2,6,...,122 */

// workspace layout in floats
#define TF_OFF   0
#define TF_SZ    (NB*COLS)
#define TFT_OFF  (TF_OFF + TF_SZ)
#define TFT_SZ   (NB*NFR*NCOEF)
#define CUR_OFF  (TFT_OFF + TFT_SZ)
#define CUR_SZ   (NB*4*NCOEF*2)
#define CK_OFF   (CUR_OFF + CUR_SZ)
#define CK_SZ    (NCK*NB*NCOEF*2)
#define WINT_OFF (CK_OFF + CK_SZ)
#define WINT_SZ  (WINSZ)
#define TW_OFF   (WINT_OFF + WINT_SZ)
#define TW_SZ    (HALFW*2)
#define ZBF_OFF  (TW_OFF + TW_SZ)
#define ZBF_SZ   (NB*ZDIM/2)

// 2-bit XOR swizzle for the FFT plane: bits[3:2] ^= bits[5:4]
#define PHI(p) ((p) ^ ((((p) >> 4) & 3) << 2))

typedef short bf16x8 __attribute__((ext_vector_type(8)));
typedef float f32x4 __attribute__((ext_vector_type(4)));
typedef float f32x2 __attribute__((ext_vector_type(2)));

__device__ __forceinline__ float2 cmul(float2 a, float2 b) {
  return make_float2(a.x * b.x - a.y * b.y, a.x * b.y + a.y * b.x);
}

// packed complex multiply: 1 pk_mul + 1 pk_fma (fp-contract)
__device__ __forceinline__ f32x2 cmul2(f32x2 a, f32x2 b) {
  f32x2 t = f32x2{a.x, a.x} * b;
  return f32x2{-a.y, a.y} * f32x2{b.y, b.x} + t;
}
// multiply by -i: (d.y, -d.x)
__device__ __forceinline__ f32x2 nid(f32x2 d) { return f32x2{d.y, -d.x}; }

// LDS-only workgroup barrier: drains LDS, leaves global loads in flight.
#define WGBAR()                                              \
  do {                                                       \
    asm volatile("s_waitcnt lgkmcnt(0)" ::: "memory");       \
    __builtin_amdgcn_s_barrier();                            \
    asm volatile("" ::: "memory");                           \
  } while (0)

__device__ __forceinline__ short f2bf(float f) {
  unsigned u = __builtin_bit_cast(unsigned, f);
  u += 0x7FFFu + ((u >> 16) & 1u);      // RNE
  return (short)(u >> 16);
}

__device__ __forceinline__ void gload_lds16(const float* g, float* l) {
  __builtin_amdgcn_global_load_lds(
      (const __attribute__((address_space(1))) unsigned int*)(const void*)g,
      (__attribute__((address_space(3))) unsigned int*)(void*)l, 16, 0, 0);
}

// ---------------------------------------------------------------- init tables (+ z->bf16)
__global__ __launch_bounds__(256) void init_tables(const float* __restrict__ z,
                                                   float* __restrict__ winT,
                                                   float2* __restrict__ twG,
                                                   short* __restrict__ zbf) {
  int i = blockIdx.x * 256 + threadIdx.x;   // grid 32*256 = 8192
  if (i < WINSZ) {
    winT[i] = 0.5f - 0.5f * cosf((float)(2.0 * 3.14159265358979323846 / 2048.0) * (float)i);
  }
  if (i < HALFW) {
    float ang = (float)(-2.0 * 3.14159265358979323846 / 2048.0) * (float)i;
    float sv, cv;
    sincosf(ang, &sv, &cv);
    twG[i] = make_float2(cv, sv);
  }
  if (i < NB * ZDIM) zbf[i] = f2bf(z[i]);
}

// ---------------------------------------------------------------- MFMA GEMM + squash
// 32-col tiles (grid 4100): W tile 128x32 f32 = 16KB LDS -> deep cross-block
// fetch overlap. Wave w owns rows 16w..16w+15.
__global__ __launch_bounds__(256) void tf_gemm_mfma(const short* __restrict__ zbf,
                                                    const float* __restrict__ W,
                                                    const float* __restrict__ bias,
                                                    float* __restrict__ tf) {
  __shared__ float Wt[128 * 32];   // [k][col], 16 KB
  int tid = threadIdx.x;
  int wave = tid >> 6, lane = tid & 63;
  int colb = blockIdx.x * 32;

#pragma unroll
  for (int it = 0; it < 4; ++it) {
    int ci = tid + it * 256;
    const float* src = W + (size_t)(ci >> 3) * COLS + colb + (ci & 7) * 4;
    gload_lds16(src, &Wt[ci * 4]);
  }

  int lr = lane & 15;
  int lk = (lane >> 4) * 8;
  int lq = (lane >> 4) * 4;

  float bv[2];
#pragma unroll
  for (int n = 0; n < 2; ++n) bv[n] = bias[colb + 16 * n + lr];

  f32x4 acc[2];
#pragma unroll
  for (int n = 0; n < 2; ++n)
    acc[n] = f32x4{bv[n], bv[n], bv[n], bv[n]};

  bf16x8 afr[4];
#pragma unroll
  for (int s = 0; s < 4; ++s)
    afr[s] = *reinterpret_cast<const bf16x8*>(zbf + (16 * wave + lr) * ZDIM + s * 32 + lk);

  __syncthreads();   // stage complete

#pragma unroll
  for (int s = 0; s < 4; ++s) {
    bf16x8 bfr[2];
#pragma unroll
    for (int n = 0; n < 2; ++n) {
      const float* wp = &Wt[(s * 32 + lk) * 32 + 16 * n + lr];
      bfr[n] = bf16x8{f2bf(wp[0 * 32]), f2bf(wp[1 * 32]), f2bf(wp[2 * 32]), f2bf(wp[3 * 32]),
                      f2bf(wp[4 * 32]), f2bf(wp[5 * 32]), f2bf(wp[6 * 32]), f2bf(wp[7 * 32])};
    }
#pragma unroll
    for (int n = 0; n < 2; ++n)
      acc[n] = __builtin_amdgcn_mfma_f32_16x16x32_bf16(afr[s], bfr[n], acc[n], 0, 0, 0);
  }

  const float RESR = (1.0f - 0.02f) * 0.99f;
#pragma unroll
  for (int n = 0; n < 2; ++n) {
    int col = colb + 16 * n + lr;
#pragma unroll
    for (int r = 0; r < 4; ++r) {
      int row = 16 * wave + lq + r;
      float x = acc[n][r];
      float sg = 1.0f / (1.0f + __expf(-x));
      tf[(size_t)row * COLS + col] = 0.02f + sg * RESR;
    }
  }
}

// ---------------------------------------------------------------- fwd 2048 FFT (radix-2)
static __device__ __forceinline__ void wg_fft2048(float* ar, float* ai,
                                                  float* br, float* bi,
                                                  const float2* tw,
                                                  float** outr, float** outi) {
  float *xr = ar, *xi = ai, *yr = br, *yi = bi;
  int m = 1;
  for (int s = 0; s < 11; ++s) {
    __syncthreads();
#pragma unroll
    for (int it = 0; it < 4; ++it) {
      int t = (int)threadIdx.x + it * 256;
      int jm = t & ~(m - 1);
      float x0r = xr[t], x0i = xi[t];
      float x1r = xr[t + 1024], x1i = xi[t + 1024];
      float2 w = tw[jm];
      float sr = x0r + x1r, si = x0i + x1i;
      float dr = x0r - x1r, di = x0i - x1i;
      float pr = dr * w.x - di * w.y;
      float pi = dr * w.y + di * w.x;
      yr[t + jm] = sr;      yi[t + jm] = si;
      yr[t + jm + m] = pr;  yi[t + jm + m] = pi;
    }
    float* t0 = xr; xr = yr; yr = t0;
    float* t1 = xi; xi = yi; yi = t1;
    m <<= 1;
  }
  __syncthreads();
  *outr = xr; *outi = xi;
}

__global__ __launch_bounds__(256) void fwd_fft_kernel(const float* __restrict__ imp,
                                                      const float* __restrict__ winT,
                                                      const float2* __restrict__ twG,
                                                      float2* __restrict__ cur) {
  __shared__ float b0r[WINSZ], b0i[WINSZ], b1r[WINSZ], b1i[WINSZ];
  __shared__ float2 tw[HALFW];
  int wg = blockIdx.x;
  int b = wg >> 2, f = wg & 3;
  int tid = threadIdx.x;

  for (int i = tid; i < HALFW; i += 256) tw[i] = twG[i];
  for (int w = tid; w < WINSZ; w += 256) {
    int s = f * HALFW + w;
    float v = (s < IMPN) ? imp[(size_t)b * IMPN + s] * winT[w] : 0.0f;
    b0r[w] = v;
    b0i[w] = 0.0f;
  }
  float *rr, *ri;
  wg_fft2048(b0r, b0i, b1r, b1i, tw, &rr, &ri);
  for (int k = tid; k < NCOEF; k += 256)
    cur[(size_t)wg * NCOEF + k] = make_float2(rr[k], ri[k]);
}

// ---------------------------------------------------------------- recurrence checkpoints + tf transpose
__global__ __launch_bounds__(256) void recur_ck_t(const float* __restrict__ tf,
                                                  const float2* __restrict__ cur,
                                                  float2* __restrict__ ckp,
                                                  float* __restrict__ tft) {
  int id = blockIdx.x * 256 + threadIdx.x;
  if (id >= NB * NCOEF) return;
  int b = id / NCOEF;
  int k = id - b * NCOEF;

  float g = 3.14159265358979323846f * (float)k / 1024.0f;
  float sg, cg;
  sincosf(g, &sg, &cg);
  bool herm = (k == 0) || (k == HALFW);

  const float4* tf4 = (const float4*)(tf + (size_t)b * COLS + (size_t)k * NFR);
  const float2* curb = cur + (size_t)b * 4 * NCOEF + k;
  float* tftb = tft + (size_t)b * NFR * NCOEF + k;

  float pre = 0.0f, pim = 0.0f;
  for (int f4 = 0; f4 < 32; ++f4) {
    float4 tv = tf4[f4];
    float tfs[4] = {tv.x, tv.y, tv.z, tv.w};
#pragma unroll
    for (int u = 0; u < 4; ++u) {
      int f = 4 * f4 + u;
      tftb[(size_t)f * NCOEF] = tfs[u];       // coalesced transpose write
      if (f < 124) {
        float tfv = tfs[u];
        float cr = 0.0f, ci = 0.0f;
        if (f < 4) {
          float2 cv = curb[(size_t)f * NCOEF];
          cr = cv.x; ci = cv.y;
        }
        float ire = herm ? 0.0f : pim;
        float rre = fmaf(pre, cg, ire * sg);
        float rim = -fmaf(pre, sg, ire * cg);
        float sre = (cr + rre) * tfv;
        float sim = (ci + rim) * tfv;
        if ((f & 3) == 2)
          ckp[(size_t)((f - 2) >> 2) * NB * NCOEF + (size_t)b * NCOEF + k] = make_float2(sre, sim);
        pre = sre; pim = sim;
      }
    }
  }
}

// ---------------------------------------------------------------- fused recur + irfft + OLA
// Register DIF radix-4; P/Q planes; 3 LDS-only barriers/frame. All complex
// arithmetic in f32x2 vector form -> v_pk_*_f32 (VOP3P dual-issue). Scale
// folded into window constants.
__global__ __launch_bounds__(256) void fused_resyn(const float* __restrict__ tft,
                                                   const float2* __restrict__ cur,
                                                   const float2* __restrict__ ckp,
                                                   const float* __restrict__ winT,
                                                   const float2* __restrict__ twG,
                                                   float* __restrict__ out) {
  __shared__ f32x2 P[1024];   // X plane (mirror source)
  __shared__ f32x2 Q[1024];   // butterfly work plane

  int bidx = blockIdx.x;
  int b = bidx >> 5, c = bidx & 31;
  int t = threadIdx.x;

  // ---- recurrence slots: k = t + 256*i (i<4); thread 0 also owns k=1024
  float pre[5], pim[5], cgv[5], sgv[5];
#pragma unroll
  for (int i = 0; i < 5; ++i) {
    if (i == 4) { cgv[4] = -1.0f; sgv[4] = 0.0f; }
    else {
      float2 tv = twG[t + 256 * i];
      cgv[i] = tv.x; sgv[i] = -tv.y;       // cos/sin(pi*k/1024)
    }
    pre[i] = 0.0f; pim[i] = 0.0f;
  }
  if (c > 0) {
    const float2* ck = ckp + ((size_t)(c - 1) * NB + b) * NCOEF;
#pragma unroll
    for (int i = 0; i < 5; ++i) {
      if (i == 4 && t != 0) continue;
      int k = (i == 4) ? 1024 : t + 256 * i;
      float2 v = ck[k];
      pre[i] = v.x; pim[i] = v.y;
    }
  }

  // ---- base twiddles only (squares/cubes recomputed per frame, packed)
  float2 tl;
  tl = twG[2 * t];          f32x2 w1a = f32x2{tl.x, tl.y};
  tl = twG[8 * (t & 63)];   f32x2 w2a = f32x2{tl.x, tl.y};
  tl = twG[32 * (t & 15)];  f32x2 w3a = f32x2{tl.x, tl.y};
  tl = twG[128 * (t & 3)];  f32x2 w4a = f32x2{tl.x, tl.y};
  tl = twG[t];              f32x2 twp0 = f32x2{tl.x, tl.y};

  // ---- extract constants (digit-reversed positions); 1/2048 scale folded in
  const float Cs = 0.5f / 1024.0f;
  int mb = (t >> 6) + ((t >> 4) & 3) * 4 + ((t >> 2) & 3) * 16 + (t & 3) * 64;
  const float2* win2 = (const float2*)winT;
  f32x2 wv0, wv1, wv2, wv3;
  { float2 w = win2[mb];       wv0 = f32x2{w.x * Cs, w.y * Cs}; }
  { float2 w = win2[mb + 256]; wv1 = f32x2{w.x * Cs, w.y * Cs}; }
  { float2 w = win2[mb + 512]; wv2 = f32x2{w.x * Cs, w.y * Cs}; }
  { float2 w = win2[mb + 768]; wv3 = f32x2{w.x * Cs, w.y * Cs}; }

  // ---- LDS address constants (swizzled)
  int X0 = PHI(t);
  int B2 = 256 * (t >> 6) + ((t & 63) ^ (((t >> 4) & 3) << 2));
  int b3h = 64 * (t >> 4), i3 = t & 15;
  int b4h = 16 * (t >> 2), i4 = t & 3, c4 = (t >> 2) & 3;
  int p5 = b4h + 4 * ((t & 3) ^ c4);
  int pm0 = PHI((1024 - t) & 1023);
  int pm1 = PHI((1024 - (t + 256)) & 1023);
  int pm2 = PHI((1024 - (t + 512)) & 1023);
  int pm3 = PHI((1024 - (t + 768)) & 1023);

  const float* tftb = tft + (size_t)b * NFR * NCOEF;
  const float2* curb = cur + (size_t)b * 4 * NCOEF;

  int fs = (c == 0) ? 0 : 4 * c - 1;
  int fe = 4 * c + 3;
  f32x2 car0 = f32x2{0.0f, 0.0f}, car1 = f32x2{0.0f, 0.0f};

  // ---- tf prefetch for frame fs
  float ntf[5];
  {
    const float* tfr = tftb + (size_t)fs * NCOEF;
#pragma unroll
    for (int i = 0; i < 4; ++i) ntf[i] = tfr[t + 256 * i];
    ntf[4] = (t == 0) ? tfr[1024] : 0.0f;
  }

#define KEEP(x) asm volatile("" : "+v"(x))

  for (int f = fs; f <= fe; ++f) {
    // tie base twiddles so derived powers are recomputed (not hoisted)
    KEEP(w1a); KEEP(w2a); KEEP(w3a); KEEP(w4a); KEEP(twp0);

    float ctf[5];
#pragma unroll
    for (int i = 0; i < 5; ++i) ctf[i] = ntf[i];

    // ---- issue next frame's tf loads (hide under this frame's FFT)
    if (f < fe) {
      const float* tfr = tftb + (size_t)(f + 1) * NCOEF;
#pragma unroll
      for (int i = 0; i < 4; ++i) ntf[i] = tfr[t + 256 * i];
      ntf[4] = (t == 0) ? tfr[1024] : 0.0f;
    }

    // ---- advance recurrence (registers)
    float S[5], I[5];
#pragma unroll
    for (int i = 0; i < 5; ++i) {
      if (i == 4 && t != 0) { S[4] = 0.0f; I[4] = 0.0f; continue; }
      float cr = 0.0f, ci = 0.0f;
      if (f < 4) {
        int k = (i == 4) ? 1024 : t + 256 * i;
        float2 cv = curb[(size_t)f * NCOEF + k];
        cr = cv.x; ci = cv.y;
      }
      float rre = fmaf(pre[i], cgv[i], pim[i] * sgv[i]);
      float rim = -fmaf(pre[i], sgv[i], pim[i] * cgv[i]);
      S[i] = (cr + rre) * ctf[i];
      I[i] = (ci + rim) * ctf[i];
      pre[i] = S[i]; pim[i] = I[i];
    }

    // ---- X into P
#pragma unroll
    for (int i = 0; i < 4; ++i)
      P[X0 + 256 * i] = f32x2{S[i], I[i]};
    WGBAR();                               // (alpha) X visible

    // ---- pack Z (own X from regs; mirror from P) + stage-1 butterfly (packed)
    const float R2 = 0.70710678118654752f;
    f32x2 twp1 = cmul2(twp0, f32x2{R2, -R2});
    f32x2 twp2 = f32x2{twp0.y, -twp0.x};
    f32x2 twp3 = f32x2{twp1.y, -twp1.x};
    f32x2 Z[4];
    {
      f32x2 xm[4];
      xm[0] = (t == 0) ? f32x2{S[4], 0.0f} : P[pm0];
      xm[1] = P[pm1]; xm[2] = P[pm2]; xm[3] = P[pm3];
      f32x2 twp[4] = {twp0, twp1, twp2, twp3};
#pragma unroll
      for (int i = 0; i < 4; ++i) {
        f32x2 x = f32x2{S[i], I[i]};
        f32x2 cjm = f32x2{xm[i].x, -xm[i].y};        // conj(mirror)
        f32x2 xe = x + cjm;
        f32x2 xp = x - cjm;
        f32x2 Xo = cmul2(xp, f32x2{twp[i].x, -twp[i].y});   // * e^{+2pi i j/2048}
        Z[i] = f32x2{xe.x - Xo.y, -(xe.y + Xo.x)};
      }
    }
    f32x2 y0, y1, y2, y3;
    {
      f32x2 w1b = cmul2(w1a, w1a);
      f32x2 w1c = cmul2(w1b, w1a);
      f32x2 A = Z[0] + Z[2];
      f32x2 B = Z[0] - Z[2];
      f32x2 C = Z[1] + Z[3];
      f32x2 D = Z[1] - Z[3];
      f32x2 nD = nid(D);
      y0 = A + C;
      y1 = cmul2(B + nD, w1a);
      y2 = cmul2(A - C, w1b);
      y3 = cmul2(B - nD, w1c);
    }
    WGBAR();                               // (beta) prev stage-5 reads of Q done
    Q[X0]       = y0;
    Q[X0 + 256] = y1;
    Q[X0 + 512] = y2;
    Q[X0 + 768] = y3;
    WGBAR();                               // (gamma) y visible across waves

    // ---- stage 2 (wave-local, N=256)
    {
      f32x2 u0 = Q[B2], u1 = Q[B2 + 64], u2 = Q[B2 + 128], u3 = Q[B2 + 192];
      f32x2 w2b = cmul2(w2a, w2a);
      f32x2 w2c = cmul2(w2b, w2a);
      f32x2 A = u0 + u2, B = u0 - u2, C = u1 + u3, D = u1 - u3;
      f32x2 nD = nid(D);
      Q[B2]       = A + C;
      Q[B2 + 64]  = cmul2(B + nD, w2a);
      Q[B2 + 128] = cmul2(A - C, w2b);
      Q[B2 + 192] = cmul2(B - nD, w2c);
    }
    asm volatile("s_waitcnt lgkmcnt(0)" ::: "memory");

    // ---- stage 3 (N=64)
    {
      f32x2 u0 = Q[b3h + i3];
      f32x2 u1 = Q[b3h + 16 + (i3 ^ 4)];
      f32x2 u2 = Q[b3h + 32 + (i3 ^ 8)];
      f32x2 u3 = Q[b3h + 48 + (i3 ^ 12)];
      f32x2 w3b = cmul2(w3a, w3a);
      f32x2 w3c = cmul2(w3b, w3a);
      f32x2 A = u0 + u2, B = u0 - u2, C = u1 + u3, D = u1 - u3;
      f32x2 nD = nid(D);
      Q[b3h + i3]             = A + C;
      Q[b3h + 16 + (i3 ^ 4)]  = cmul2(B + nD, w3a);
      Q[b3h + 32 + (i3 ^ 8)]  = cmul2(A - C, w3b);
      Q[b3h + 48 + (i3 ^ 12)] = cmul2(B - nD, w3c);
    }
    asm volatile("s_waitcnt lgkmcnt(0)" ::: "memory");

    // ---- stage 4 (N=16)
    {
      f32x2 u0 = Q[b4h + 4 * (0 ^ c4) + i4];
      f32x2 u1 = Q[b4h + 4 * (1 ^ c4) + i4];
      f32x2 u2 = Q[b4h + 4 * (2 ^ c4) + i4];
      f32x2 u3 = Q[b4h + 4 * (3 ^ c4) + i4];
      f32x2 w4b = cmul2(w4a, w4a);
      f32x2 w4c = cmul2(w4b, w4a);
      f32x2 A = u0 + u2, B = u0 - u2, C = u1 + u3, D = u1 - u3;
      f32x2 nD = nid(D);
      Q[b4h + 4 * (0 ^ c4) + i4] = A + C;
      Q[b4h + 4 * (1 ^ c4) + i4] = cmul2(B + nD, w4a);
      Q[b4h + 4 * (2 ^ c4) + i4] = cmul2(A - C, w4b);
      Q[b4h + 4 * (3 ^ c4) + i4] = cmul2(B - nD, w4c);
    }
    asm volatile("s_waitcnt lgkmcnt(0)" ::: "memory");

    // ---- stage 5 (N=4, no twiddles) -> regs
    float4 q01 = *reinterpret_cast<const float4*>(&Q[p5]);
    float4 q23 = *reinterpret_cast<const float4*>(&Q[p5 + 2]);
    f32x2 z0, z1, z2, z3;
    {
      f32x2 a = f32x2{q01.x, q01.y}, bq = f32x2{q01.z, q01.w};
      f32x2 cq = f32x2{q23.x, q23.y}, d = f32x2{q23.z, q23.w};
      f32x2 A = a + cq, B = a - cq, C = bq + d, D = bq - d;
      f32x2 nD = nid(D);
      z0 = A + C;
      z1 = B + nD;
      z2 = A - C;
      z3 = B - nD;
    }

    // ---- extract: x[2m]=Re z[m]*wv.x, x[2m+1]=-Im z[m]*wv.y; m = mb + 256q
    f32x2 e0 = f32x2{z0.x, -z0.y} * wv0;
    f32x2 e1 = f32x2{z1.x, -z1.y} * wv1;
    f32x2 e2 = f32x2{z2.x, -z2.y} * wv2;
    f32x2 e3 = f32x2{z3.x, -z3.y} * wv3;
    if (f >= 4 * c) {
      f32x2* ob2 = (f32x2*)(out + (size_t)b * NSAMP + (size_t)f * 1024);
      ob2[mb]       = e0 + car0;
      ob2[mb + 256] = e1 + car1;
    }
    car0 = e2;
    car1 = e3;
  }
#undef KEEP
}

// ---------------------------------------------------------------- launch
extern "C" void kernel_launch(void* const* d_in, const int* in_sizes, int n_in,
                              void* d_out, int out_size, void* d_ws, size_t ws_size,
                              hipStream_t stream) {
  const float* z    = (const float*)d_in[0];
  const float* imp  = (const float*)d_in[1];
  const float* W    = (const float*)d_in[2];
  const float* bias = (const float*)d_in[3];

  float* ws = (float*)d_ws;
  float*  tf   = ws + TF_OFF;
  float*  tft  = ws + TFT_OFF;
  float2* cur  = (float2*)(ws + CUR_OFF);
  float2* ckp  = (float2*)(ws + CK_OFF);
  float*  winT = ws + WINT_OFF;
  float2* twG  = (float2*)(ws + TW_OFF);
  short*  zbf  = (short*)(ws + ZBF_OFF);
  float*  out  = (float*)d_out;

  init_tables<<<32, 256, 0, stream>>>(z, winT, twG, zbf);
  tf_gemm_mfma<<<COLS / 32, 256, 0, stream>>>(zbf, W, bias, tf);
  fwd_fft_kernel<<<NB * 4, 256, 0, stream>>>(imp, winT, twG, cur);
  recur_ck_t<<<(NB * NCOEF + 255) / 256, 256, 0, stream>>>(tf, cur, ckp, tft);
  fused_resyn<<<NB * NCHUNK, 256, 0, stream>>>(tft, cur, ckp, winT, twG, out);
}

// Round 16
// 85.764 us; speedup vs baseline: 1.1423x; 1.0007x over previous
//
#include <hip/hip_runtime.h>

#define NB 64
#define ZDIM 128
#define NCOEF 1025
#define NFR 128
#define COLS 131200          /* NCOEF*NFR */
#define WINSZ 2048
#define HALFW 1024
#define NSAMP 131072
#define IMPN 4096
#define NCHUNK 32            /* chunks of 4 spans */
#define NCK 31               /* checkpoints after frames 2,6,...,122 */

// workspace layout in floats
#define TF_OFF   0
#define TF_SZ    (NB*COLS)
#define TFT_OFF  (TF_OFF + TF_SZ)
#define TFT_SZ   (NB*NFR*NCOEF)
#define CUR_OFF  (TFT_OFF + TFT_SZ)
#define CUR_SZ   (NB*4*NCOEF*2)
#define CK_OFF   (CUR_OFF + CUR_SZ)
#define CK_SZ    (NCK*NB*NCOEF*2)
#define WINT_OFF (CK_OFF + CK_SZ)
#define WINT_SZ  (WINSZ)
#define TW_OFF   (WINT_OFF + WINT_SZ)
#define TW_SZ    (HALFW*2)
#define ZBF_OFF  (TW_OFF + TW_SZ)
#define ZBF_SZ   (NB*ZDIM/2)

// 2-bit XOR swizzle for the FFT plane: bits[3:2] ^= bits[5:4]
#define PHI(p) ((p) ^ ((((p) >> 4) & 3) << 2))

typedef short bf16x8 __attribute__((ext_vector_type(8)));
typedef float f32x4 __attribute__((ext_vector_type(4)));
typedef float f32x2 __attribute__((ext_vector_type(2)));

// packed complex multiply: 1 pk_mul + 1 pk_fma (fp-contract)
__device__ __forceinline__ f32x2 cmul2(f32x2 a, f32x2 b) {
  f32x2 t = f32x2{a.x, a.x} * b;
  return f32x2{-a.y, a.y} * f32x2{b.y, b.x} + t;
}
// multiply by -i
__device__ __forceinline__ f32x2 nid(f32x2 d) { return f32x2{d.y, -d.x}; }

// full LDS drain + barrier (cross-wave visibility)
#define WGBAR()                                              \
  do {                                                       \
    asm volatile("s_waitcnt lgkmcnt(0)" ::: "memory");       \
    __builtin_amdgcn_s_barrier();                            \
    asm volatile("" ::: "memory");                           \
  } while (0)

#define LGKM0() asm volatile("s_waitcnt lgkmcnt(0)" ::: "memory")

__device__ __forceinline__ short f2bf(float f) {
  unsigned u = __builtin_bit_cast(unsigned, f);
  u += 0x7FFFu + ((u >> 16) & 1u);      // RNE
  return (short)(u >> 16);
}

__device__ __forceinline__ void gload_lds16(const float* g, float* l) {
  __builtin_amdgcn_global_load_lds(
      (const __attribute__((address_space(1))) unsigned int*)(const void*)g,
      (__attribute__((address_space(3))) unsigned int*)(void*)l, 16, 0, 0);
}

// ---------------------------------------------------------------- init tables (+ z->bf16)
__global__ __launch_bounds__(256) void init_tables(const float* __restrict__ z,
                                                   float* __restrict__ winT,
                                                   float2* __restrict__ twG,
                                                   short* __restrict__ zbf) {
  int i = blockIdx.x * 256 + threadIdx.x;   // grid 32*256 = 8192
  if (i < WINSZ) {
    winT[i] = 0.5f - 0.5f * cosf((float)(2.0 * 3.14159265358979323846 / 2048.0) * (float)i);
  }
  if (i < HALFW) {
    float ang = (float)(-2.0 * 3.14159265358979323846 / 2048.0) * (float)i;
    float sv, cv;
    sincosf(ang, &sv, &cv);
    twG[i] = make_float2(cv, sv);
  }
  if (i < NB * ZDIM) zbf[i] = f2bf(z[i]);
}

// ---------------------------------------------------------------- MFMA GEMM + squash
// 32-col tiles (grid 4100): W tile 128x32 f32 = 16KB LDS -> deep cross-block
// fetch overlap. Wave w owns rows 16w..16w+15.
__global__ __launch_bounds__(256) void tf_gemm_mfma(const short* __restrict__ zbf,
                                                    const float* __restrict__ W,
                                                    const float* __restrict__ bias,
                                                    float* __restrict__ tf) {
  __shared__ float Wt[128 * 32];   // [k][col], 16 KB
  int tid = threadIdx.x;
  int wave = tid >> 6, lane = tid & 63;
  int colb = blockIdx.x * 32;

#pragma unroll
  for (int it = 0; it < 4; ++it) {
    int ci = tid + it * 256;
    const float* src = W + (size_t)(ci >> 3) * COLS + colb + (ci & 7) * 4;
    gload_lds16(src, &Wt[ci * 4]);
  }

  int lr = lane & 15;
  int lk = (lane >> 4) * 8;
  int lq = (lane >> 4) * 4;

  float bv[2];
#pragma unroll
  for (int n = 0; n < 2; ++n) bv[n] = bias[colb + 16 * n + lr];

  f32x4 acc[2];
#pragma unroll
  for (int n = 0; n < 2; ++n)
    acc[n] = f32x4{bv[n], bv[n], bv[n], bv[n]};

  bf16x8 afr[4];
#pragma unroll
  for (int s = 0; s < 4; ++s)
    afr[s] = *reinterpret_cast<const bf16x8*>(zbf + (16 * wave + lr) * ZDIM + s * 32 + lk);

  __syncthreads();   // stage complete

#pragma unroll
  for (int s = 0; s < 4; ++s) {
    bf16x8 bfr[2];
#pragma unroll
    for (int n = 0; n < 2; ++n) {
      const float* wp = &Wt[(s * 32 + lk) * 32 + 16 * n + lr];
      bfr[n] = bf16x8{f2bf(wp[0 * 32]), f2bf(wp[1 * 32]), f2bf(wp[2 * 32]), f2bf(wp[3 * 32]),
                      f2bf(wp[4 * 32]), f2bf(wp[5 * 32]), f2bf(wp[6 * 32]), f2bf(wp[7 * 32])};
    }
#pragma unroll
    for (int n = 0; n < 2; ++n)
      acc[n] = __builtin_amdgcn_mfma_f32_16x16x32_bf16(afr[s], bfr[n], acc[n], 0, 0, 0);
  }

  const float RESR = (1.0f - 0.02f) * 0.99f;
#pragma unroll
  for (int n = 0; n < 2; ++n) {
    int col = colb + 16 * n + lr;
#pragma unroll
    for (int r = 0; r < 4; ++r) {
      int row = 16 * wave + lq + r;
      float x = acc[n][r];
      float sg = 1.0f / (1.0f + __expf(-x));
      tf[(size_t)row * COLS + col] = 0.02f + sg * RESR;
    }
  }
}

// ---------------------------------------------------------------- fwd 2048 FFT (radix-2)
static __device__ __forceinline__ void wg_fft2048(float* ar, float* ai,
                                                  float* br, float* bi,
                                                  const float2* tw,
                                                  float** outr, float** outi) {
  float *xr = ar, *xi = ai, *yr = br, *yi = bi;
  int m = 1;
  for (int s = 0; s < 11; ++s) {
    __syncthreads();
#pragma unroll
    for (int it = 0; it < 4; ++it) {
      int t = (int)threadIdx.x + it * 256;
      int jm = t & ~(m - 1);
      float x0r = xr[t], x0i = xi[t];
      float x1r = xr[t + 1024], x1i = xi[t + 1024];
      float2 w = tw[jm];
      float sr = x0r + x1r, si = x0i + x1i;
      float dr = x0r - x1r, di = x0i - x1i;
      float pr = dr * w.x - di * w.y;
      float pi = dr * w.y + di * w.x;
      yr[t + jm] = sr;      yi[t + jm] = si;
      yr[t + jm + m] = pr;  yi[t + jm + m] = pi;
    }
    float* t0 = xr; xr = yr; yr = t0;
    float* t1 = xi; xi = yi; yi = t1;
    m <<= 1;
  }
  __syncthreads();
  *outr = xr; *outi = xi;
}

__global__ __launch_bounds__(256) void fwd_fft_kernel(const float* __restrict__ imp,
                                                      const float* __restrict__ winT,
                                                      const float2* __restrict__ twG,
                                                      float2* __restrict__ cur) {
  __shared__ float b0r[WINSZ], b0i[WINSZ], b1r[WINSZ], b1i[WINSZ];
  __shared__ float2 tw[HALFW];
  int wg = blockIdx.x;
  int b = wg >> 2, f = wg & 3;
  int tid = threadIdx.x;

  for (int i = tid; i < HALFW; i += 256) tw[i] = twG[i];
  for (int w = tid; w < WINSZ; w += 256) {
    int s = f * HALFW + w;
    float v = (s < IMPN) ? imp[(size_t)b * IMPN + s] * winT[w] : 0.0f;
    b0r[w] = v;
    b0i[w] = 0.0f;
  }
  float *rr, *ri;
  wg_fft2048(b0r, b0i, b1r, b1i, tw, &rr, &ri);
  for (int k = tid; k < NCOEF; k += 256)
    cur[(size_t)wg * NCOEF + k] = make_float2(rr[k], ri[k]);
}

// ---------------------------------------------------------------- recurrence checkpoints + tf transpose
__global__ __launch_bounds__(256) void recur_ck_t(const float* __restrict__ tf,
                                                  const float2* __restrict__ cur,
                                                  float2* __restrict__ ckp,
                                                  float* __restrict__ tft) {
  int id = blockIdx.x * 256 + threadIdx.x;
  if (id >= NB * NCOEF) return;
  int b = id / NCOEF;
  int k = id - b * NCOEF;

  float g = 3.14159265358979323846f * (float)k / 1024.0f;
  float sg, cg;
  sincosf(g, &sg, &cg);
  bool herm = (k == 0) || (k == HALFW);

  const float4* tf4 = (const float4*)(tf + (size_t)b * COLS + (size_t)k * NFR);
  const float2* curb = cur + (size_t)b * 4 * NCOEF + k;
  float* tftb = tft + (size_t)b * NFR * NCOEF + k;

  float pre = 0.0f, pim = 0.0f;
  for (int f4 = 0; f4 < 32; ++f4) {
    float4 tv = tf4[f4];
    float tfs[4] = {tv.x, tv.y, tv.z, tv.w};
#pragma unroll
    for (int u = 0; u < 4; ++u) {
      int f = 4 * f4 + u;
      tftb[(size_t)f * NCOEF] = tfs[u];       // coalesced transpose write
      if (f < 124) {
        float tfv = tfs[u];
        float cr = 0.0f, ci = 0.0f;
        if (f < 4) {
          float2 cv = curb[(size_t)f * NCOEF];
          cr = cv.x; ci = cv.y;
        }
        float ire = herm ? 0.0f : pim;
        float rre = fmaf(pre, cg, ire * sg);
        float rim = -fmaf(pre, sg, ire * cg);
        float sre = (cr + rre) * tfv;
        float sim = (ci + rim) * tfv;
        if ((f & 3) == 2)
          ckp[(size_t)((f - 2) >> 2) * NB * NCOEF + (size_t)b * NCOEF + k] = make_float2(sre, sim);
        pre = sre; pim = sim;
      }
    }
  }
}

// ---------------------------------------------------------------- fused recur + irfft + OLA
// Register DIF radix-4; P/Q planes; 3 LDS barriers/frame; lgkmcnt(0) drains
// between wave-local stages. Packed f32 math (VOP3P). Round-13 verified form.
__global__ __launch_bounds__(256) void fused_resyn(const float* __restrict__ tft,
                                                   const float2* __restrict__ cur,
                                                   const float2* __restrict__ ckp,
                                                   const float* __restrict__ winT,
                                                   const float2* __restrict__ twG,
                                                   float* __restrict__ out) {
  __shared__ f32x2 P[1024];   // X plane (mirror source)
  __shared__ f32x2 Q[1024];   // butterfly work plane

  int bidx = blockIdx.x;
  int b = bidx >> 5, c = bidx & 31;
  int t = threadIdx.x;

  // ---- recurrence slots: k = t + 256*i (i<4); thread 0 also owns k=1024
  float pre[5], pim[5], cgv[5], sgv[5];
#pragma unroll
  for (int i = 0; i < 5; ++i) {
    if (i == 4) { cgv[4] = -1.0f; sgv[4] = 0.0f; }
    else {
      float2 tv = twG[t + 256 * i];
      cgv[i] = tv.x; sgv[i] = -tv.y;       // cos/sin(pi*k/1024)
    }
    pre[i] = 0.0f; pim[i] = 0.0f;
  }
  if (c > 0) {
    const float2* ck = ckp + ((size_t)(c - 1) * NB + b) * NCOEF;
#pragma unroll
    for (int i = 0; i < 5; ++i) {
      if (i == 4 && t != 0) continue;
      int k = (i == 4) ? 1024 : t + 256 * i;
      float2 v = ck[k];
      pre[i] = v.x; pim[i] = v.y;
    }
  }

  // ---- base twiddles only (squares/cubes recomputed per frame, packed)
  float2 tl;
  tl = twG[2 * t];          f32x2 w1a = f32x2{tl.x, tl.y};
  tl = twG[8 * (t & 63)];   f32x2 w2a = f32x2{tl.x, tl.y};
  tl = twG[32 * (t & 15)];  f32x2 w3a = f32x2{tl.x, tl.y};
  tl = twG[128 * (t & 3)];  f32x2 w4a = f32x2{tl.x, tl.y};
  tl = twG[t];              f32x2 twp0 = f32x2{tl.x, tl.y};

  // ---- extract constants (digit-reversed positions); 1/2048 scale folded in
  const float Cs = 0.5f / 1024.0f;
  int mb = (t >> 6) + ((t >> 4) & 3) * 4 + ((t >> 2) & 3) * 16 + (t & 3) * 64;
  const float2* win2 = (const float2*)winT;
  f32x2 wv0, wv1, wv2, wv3;
  { float2 w = win2[mb];       wv0 = f32x2{w.x * Cs, w.y * Cs}; }
  { float2 w = win2[mb + 256]; wv1 = f32x2{w.x * Cs, w.y * Cs}; }
  { float2 w = win2[mb + 512]; wv2 = f32x2{w.x * Cs, w.y * Cs}; }
  { float2 w = win2[mb + 768]; wv3 = f32x2{w.x * Cs, w.y * Cs}; }

  // ---- LDS address constants (swizzled)
  int X0 = PHI(t);
  int B2 = 256 * (t >> 6) + ((t & 63) ^ (((t >> 4) & 3) << 2));
  int b3h = 64 * (t >> 4), i3 = t & 15;
  int b4h = 16 * (t >> 2), i4 = t & 3, c4 = (t >> 2) & 3;
  int p5 = b4h + 4 * ((t & 3) ^ c4);
  int pm0 = PHI((1024 - t) & 1023);
  int pm1 = PHI((1024 - (t + 256)) & 1023);
  int pm2 = PHI((1024 - (t + 512)) & 1023);
  int pm3 = PHI((1024 - (t + 768)) & 1023);

  const float* tftb = tft + (size_t)b * NFR * NCOEF;
  const float2* curb = cur + (size_t)b * 4 * NCOEF;

  int fs = (c == 0) ? 0 : 4 * c - 1;
  int fe = 4 * c + 3;
  f32x2 car0 = f32x2{0.0f, 0.0f}, car1 = f32x2{0.0f, 0.0f};

  // ---- tf prefetch for frame fs
  float ntf[5];
  {
    const float* tfr = tftb + (size_t)fs * NCOEF;
#pragma unroll
    for (int i = 0; i < 4; ++i) ntf[i] = tfr[t + 256 * i];
    ntf[4] = (t == 0) ? tfr[1024] : 0.0f;
  }

#define KEEP(x) asm volatile("" : "+v"(x))

  for (int f = fs; f <= fe; ++f) {
    // tie base twiddles so derived powers are recomputed (not hoisted)
    KEEP(w1a); KEEP(w2a); KEEP(w3a); KEEP(w4a); KEEP(twp0);

    float ctf[5];
#pragma unroll
    for (int i = 0; i < 5; ++i) ctf[i] = ntf[i];

    // ---- issue next frame's tf loads (hide under this frame's FFT)
    if (f < fe) {
      const float* tfr = tftb + (size_t)(f + 1) * NCOEF;
#pragma unroll
      for (int i = 0; i < 4; ++i) ntf[i] = tfr[t + 256 * i];
      ntf[4] = (t == 0) ? tfr[1024] : 0.0f;
    }

    // ---- advance recurrence (registers)
    float S[5], I[5];
#pragma unroll
    for (int i = 0; i < 5; ++i) {
      if (i == 4 && t != 0) { S[4] = 0.0f; I[4] = 0.0f; continue; }
      float cr = 0.0f, ci = 0.0f;
      if (f < 4) {
        int k = (i == 4) ? 1024 : t + 256 * i;
        float2 cv = curb[(size_t)f * NCOEF + k];
        cr = cv.x; ci = cv.y;
      }
      float rre = fmaf(pre[i], cgv[i], pim[i] * sgv[i]);
      float rim = -fmaf(pre[i], sgv[i], pim[i] * cgv[i]);
      S[i] = (cr + rre) * ctf[i];
      I[i] = (ci + rim) * ctf[i];
      pre[i] = S[i]; pim[i] = I[i];
    }

    // ---- X into P
#pragma unroll
    for (int i = 0; i < 4; ++i)
      P[X0 + 256 * i] = f32x2{S[i], I[i]};
    WGBAR();                               // (alpha) X visible

    // ---- pack Z (own X from regs; mirror from P) + stage-1 butterfly (packed)
    const float R2 = 0.70710678118654752f;
    f32x2 twp1 = cmul2(twp0, f32x2{R2, -R2});
    f32x2 twp2 = f32x2{twp0.y, -twp0.x};
    f32x2 twp3 = f32x2{twp1.y, -twp1.x};
    f32x2 Z[4];
    {
      f32x2 xm[4];
      xm[0] = (t == 0) ? f32x2{S[4], 0.0f} : P[pm0];
      xm[1] = P[pm1]; xm[2] = P[pm2]; xm[3] = P[pm3];
      f32x2 twp[4] = {twp0, twp1, twp2, twp3};
#pragma unroll
      for (int i = 0; i < 4; ++i) {
        f32x2 x = f32x2{S[i], I[i]};
        f32x2 cjm = f32x2{xm[i].x, -xm[i].y};        // conj(mirror)
        f32x2 xe = x + cjm;
        f32x2 xp = x - cjm;
        f32x2 Xo = cmul2(xp, f32x2{twp[i].x, -twp[i].y});   // * e^{+2pi i j/2048}
        Z[i] = f32x2{xe.x - Xo.y, -(xe.y + Xo.x)};
      }
    }
    f32x2 y0, y1, y2, y3;
    {
      f32x2 w1b = cmul2(w1a, w1a);
      f32x2 w1c = cmul2(w1b, w1a);
      f32x2 A = Z[0] + Z[2];
      f32x2 B = Z[0] - Z[2];
      f32x2 C = Z[1] + Z[3];
      f32x2 D = Z[1] - Z[3];
      f32x2 nD = nid(D);
      y0 = A + C;
      y1 = cmul2(B + nD, w1a);
      y2 = cmul2(A - C, w1b);
      y3 = cmul2(B - nD, w1c);
    }
    WGBAR();                               // (beta) prev stage-5 reads of Q done
    Q[X0]       = y0;
    Q[X0 + 256] = y1;
    Q[X0 + 512] = y2;
    Q[X0 + 768] = y3;
    WGBAR();                               // (gamma) y visible across waves

    // ---- stage 2 (wave-local, N=256)
    {
      f32x2 u0 = Q[B2], u1 = Q[B2 + 64], u2 = Q[B2 + 128], u3 = Q[B2 + 192];
      f32x2 w2b = cmul2(w2a, w2a);
      f32x2 w2c = cmul2(w2b, w2a);
      f32x2 A = u0 + u2, B = u0 - u2, C = u1 + u3, D = u1 - u3;
      f32x2 nD = nid(D);
      Q[B2]       = A + C;
      Q[B2 + 64]  = cmul2(B + nD, w2a);
      Q[B2 + 128] = cmul2(A - C, w2b);
      Q[B2 + 192] = cmul2(B - nD, w2c);
    }
    LGKM0();

    // ---- stage 3 (N=64)
    {
      f32x2 u0 = Q[b3h + i3];
      f32x2 u1 = Q[b3h + 16 + (i3 ^ 4)];
      f32x2 u2 = Q[b3h + 32 + (i3 ^ 8)];
      f32x2 u3 = Q[b3h + 48 + (i3 ^ 12)];
      f32x2 w3b = cmul2(w3a, w3a);
      f32x2 w3c = cmul2(w3b, w3a);
      f32x2 A = u0 + u2, B = u0 - u2, C = u1 + u3, D = u1 - u3;
      f32x2 nD = nid(D);
      Q[b3h + i3]             = A + C;
      Q[b3h + 16 + (i3 ^ 4)]  = cmul2(B + nD, w3a);
      Q[b3h + 32 + (i3 ^ 8)]  = cmul2(A - C, w3b);
      Q[b3h + 48 + (i3 ^ 12)] = cmul2(B - nD, w3c);
    }
    LGKM0();

    // ---- stage 4 (N=16)
    {
      f32x2 u0 = Q[b4h + 4 * (0 ^ c4) + i4];
      f32x2 u1 = Q[b4h + 4 * (1 ^ c4) + i4];
      f32x2 u2 = Q[b4h + 4 * (2 ^ c4) + i4];
      f32x2 u3 = Q[b4h + 4 * (3 ^ c4) + i4];
      f32x2 w4b = cmul2(w4a, w4a);
      f32x2 w4c = cmul2(w4b, w4a);
      f32x2 A = u0 + u2, B = u0 - u2, C = u1 + u3, D = u1 - u3;
      f32x2 nD = nid(D);
      Q[b4h + 4 * (0 ^ c4) + i4] = A + C;
      Q[b4h + 4 * (1 ^ c4) + i4] = cmul2(B + nD, w4a);
      Q[b4h + 4 * (2 ^ c4) + i4] = cmul2(A - C, w4b);
      Q[b4h + 4 * (3 ^ c4) + i4] = cmul2(B - nD, w4c);
    }
    LGKM0();

    // ---- stage 5 (N=4, no twiddles) -> regs
    float4 q01 = *reinterpret_cast<const float4*>(&Q[p5]);
    float4 q23 = *reinterpret_cast<const float4*>(&Q[p5 + 2]);
    f32x2 z0, z1, z2, z3;
    {
      f32x2 a = f32x2{q01.x, q01.y}, bq = f32x2{q01.z, q01.w};
      f32x2 cq = f32x2{q23.x, q23.y}, d = f32x2{q23.z, q23.w};
      f32x2 A = a + cq, B = a - cq, C = bq + d, D = bq - d;
      f32x2 nD = nid(D);
      z0 = A + C;
      z1 = B + nD;
      z2 = A - C;
      z3 = B - nD;
    }

    // ---- extract: x[2m]=Re z[m]*wv.x, x[2m+1]=-Im z[m]*wv.y; m = mb + 256q
    f32x2 e0 = f32x2{z0.x, -z0.y} * wv0;
    f32x2 e1 = f32x2{z1.x, -z1.y} * wv1;
    f32x2 e2 = f32x2{z2.x, -z2.y} * wv2;
    f32x2 e3 = f32x2{z3.x, -z3.y} * wv3;
    if (f >= 4 * c) {
      f32x2* ob2 = (f32x2*)(out + (size_t)b * NSAMP + (size_t)f * 1024);
      ob2[mb]       = e0 + car0;
      ob2[mb + 256] = e1 + car1;
    }
    car0 = e2;
    car1 = e3;
  }
#undef KEEP
}

// ---------------------------------------------------------------- launch
extern "C" void kernel_launch(void* const* d_in, const int* in_sizes, int n_in,
                              void* d_out, int out_size, void* d_ws, size_t ws_size,
                              hipStream_t stream) {
  const float* z    = (const float*)d_in[0];
  const float* imp  = (const float*)d_in[1];
  const float* W    = (const float*)d_in[2];
  const float* bias = (const float*)d_in[3];

  float* ws = (float*)d_ws;
  float*  tf   = ws + TF_OFF;
  float*  tft  = ws + TFT_OFF;
  float2* cur  = (float2*)(ws + CUR_OFF);
  float2* ckp  = (float2*)(ws + CK_OFF);
  float*  winT = ws + WINT_OFF;
  float2* twG  = (float2*)(ws + TW_OFF);
  short*  zbf  = (short*)(ws + ZBF_OFF);
  float*  out  = (float*)d_out;

  init_tables<<<32, 256, 0, stream>>>(z, winT, twG, zbf);
  tf_gemm_mfma<<<COLS / 32, 256, 0, stream>>>(zbf, W, bias, tf);
  fwd_fft_kernel<<<NB * 4, 256, 0, stream>>>(imp, winT, twG, cur);
  recur_ck_t<<<(NB * NCOEF + 255) / 256, 256, 0, stream>>>(tf, cur, ckp, tft);
  fused_resyn<<<NB * NCHUNK, 256, 0, stream>>>(tft, cur, ckp, winT, twG, out);
}

// Round 17
// 85.528 us; speedup vs baseline: 1.1455x; 1.0028x over previous
//
#include <hip/hip_runtime.h>

#define NB 64
#define ZDIM 128
#define NCOEF 1025
#define NFR 128
#define COLS 131200          /* NCOEF*NFR */
#define WINSZ 2048
#define HALFW 1024
#define NSAMP 131072
#define IMPN 4096
#define NCHUNK 32            /* chunks of 4 spans */
#define NCK 31               /* checkpoints after frames 2,6,...,122 */

// workspace layout in floats
#define TF_OFF   0
#define TF_SZ    (NB*COLS)
#define TFT_OFF  (TF_OFF + TF_SZ)
#define TFT_SZ   (NB*NFR*NCOEF)
#define CUR_OFF  (TFT_OFF + TFT_SZ)
#define CUR_SZ   (NB*4*NCOEF*2)
#define CK_OFF   (CUR_OFF + CUR_SZ)
#define CK_SZ    (NCK*NB*NCOEF*2)
#define WINT_OFF (CK_OFF + CK_SZ)
#define WINT_SZ  (WINSZ)
#define TW_OFF   (WINT_OFF + WINT_SZ)
#define TW_SZ    (HALFW*2)
#define ZBF_OFF  (TW_OFF + TW_SZ)
#define ZBF_SZ   (NB*ZDIM/2)

// 2-bit XOR swizzle for the FFT plane: bits[3:2] ^= bits[5:4]
#define PHI(p) ((p) ^ ((((p) >> 4) & 3) << 2))

typedef short bf16x8 __attribute__((ext_vector_type(8)));
typedef float f32x4 __attribute__((ext_vector_type(4)));
typedef float f32x2 __attribute__((ext_vector_type(2)));

// packed complex multiply: 1 pk_mul + 1 pk_fma (fp-contract)
__device__ __forceinline__ f32x2 cmul2(f32x2 a, f32x2 b) {
  f32x2 t = f32x2{a.x, a.x} * b;
  return f32x2{-a.y, a.y} * f32x2{b.y, b.x} + t;
}
// multiply by -i
__device__ __forceinline__ f32x2 nid(f32x2 d) { return f32x2{d.y, -d.x}; }

// full LDS drain + barrier (cross-wave visibility)
#define WGBAR()                                              \
  do {                                                       \
    asm volatile("s_waitcnt lgkmcnt(0)" ::: "memory");       \
    __builtin_amdgcn_s_barrier();                            \
    asm volatile("" ::: "memory");                           \
  } while (0)

// compiler-only fence for wave-local stage boundaries: pins DS issue order;
// the per-wave DS pipe executes in order, and the compiler's own counted
// lgkmcnt waits cover data use. (Exonerated by rounds 14/15: identical
// failure absmax under strict vs relaxed sync => failures were the shelved
// fwd-merge, not this.)
#define PIPEFENCE() asm volatile("" ::: "memory")

__device__ __forceinline__ short f2bf(float f) {
  unsigned u = __builtin_bit_cast(unsigned, f);
  u += 0x7FFFu + ((u >> 16) & 1u);      // RNE
  return (short)(u >> 16);
}

__device__ __forceinline__ void gload_lds16(const float* g, float* l) {
  __builtin_amdgcn_global_load_lds(
      (const __attribute__((address_space(1))) unsigned int*)(const void*)g,
      (__attribute__((address_space(3))) unsigned int*)(void*)l, 16, 0, 0);
}

// ---------------------------------------------------------------- init tables (+ z->bf16)
__global__ __launch_bounds__(256) void init_tables(const float* __restrict__ z,
                                                   float* __restrict__ winT,
                                                   float2* __restrict__ twG,
                                                   short* __restrict__ zbf) {
  int i = blockIdx.x * 256 + threadIdx.x;   // grid 32*256 = 8192
  if (i < WINSZ) {
    winT[i] = 0.5f - 0.5f * cosf((float)(2.0 * 3.14159265358979323846 / 2048.0) * (float)i);
  }
  if (i < HALFW) {
    float ang = (float)(-2.0 * 3.14159265358979323846 / 2048.0) * (float)i;
    float sv, cv;
    sincosf(ang, &sv, &cv);
    twG[i] = make_float2(cv, sv);
  }
  if (i < NB * ZDIM) zbf[i] = f2bf(z[i]);
}

// ---------------------------------------------------------------- MFMA GEMM + squash
// 32-col tiles (grid 4100): W tile 128x32 f32 = 16KB LDS -> deep cross-block
// fetch overlap. Wave w owns rows 16w..16w+15.
__global__ __launch_bounds__(256) void tf_gemm_mfma(const short* __restrict__ zbf,
                                                    const float* __restrict__ W,
                                                    const float* __restrict__ bias,
                                                    float* __restrict__ tf) {
  __shared__ float Wt[128 * 32];   // [k][col], 16 KB
  int tid = threadIdx.x;
  int wave = tid >> 6, lane = tid & 63;
  int colb = blockIdx.x * 32;

#pragma unroll
  for (int it = 0; it < 4; ++it) {
    int ci = tid + it * 256;
    const float* src = W + (size_t)(ci >> 3) * COLS + colb + (ci & 7) * 4;
    gload_lds16(src, &Wt[ci * 4]);
  }

  int lr = lane & 15;
  int lk = (lane >> 4) * 8;
  int lq = (lane >> 4) * 4;

  float bv[2];
#pragma unroll
  for (int n = 0; n < 2; ++n) bv[n] = bias[colb + 16 * n + lr];

  f32x4 acc[2];
#pragma unroll
  for (int n = 0; n < 2; ++n)
    acc[n] = f32x4{bv[n], bv[n], bv[n], bv[n]};

  bf16x8 afr[4];
#pragma unroll
  for (int s = 0; s < 4; ++s)
    afr[s] = *reinterpret_cast<const bf16x8*>(zbf + (16 * wave + lr) * ZDIM + s * 32 + lk);

  __syncthreads();   // stage complete

#pragma unroll
  for (int s = 0; s < 4; ++s) {
    bf16x8 bfr[2];
#pragma unroll
    for (int n = 0; n < 2; ++n) {
      const float* wp = &Wt[(s * 32 + lk) * 32 + 16 * n + lr];
      bfr[n] = bf16x8{f2bf(wp[0 * 32]), f2bf(wp[1 * 32]), f2bf(wp[2 * 32]), f2bf(wp[3 * 32]),
                      f2bf(wp[4 * 32]), f2bf(wp[5 * 32]), f2bf(wp[6 * 32]), f2bf(wp[7 * 32])};
    }
#pragma unroll
    for (int n = 0; n < 2; ++n)
      acc[n] = __builtin_amdgcn_mfma_f32_16x16x32_bf16(afr[s], bfr[n], acc[n], 0, 0, 0);
  }

  const float RESR = (1.0f - 0.02f) * 0.99f;
#pragma unroll
  for (int n = 0; n < 2; ++n) {
    int col = colb + 16 * n + lr;
#pragma unroll
    for (int r = 0; r < 4; ++r) {
      int row = 16 * wave + lq + r;
      float x = acc[n][r];
      float sg = 1.0f / (1.0f + __expf(-x));
      tf[(size_t)row * COLS + col] = 0.02f + sg * RESR;
    }
  }
}

// ---------------------------------------------------------------- fwd 2048 FFT (radix-2)
static __device__ __forceinline__ void wg_fft2048(float* ar, float* ai,
                                                  float* br, float* bi,
                                                  const float2* tw,
                                                  float** outr, float** outi) {
  float *xr = ar, *xi = ai, *yr = br, *yi = bi;
  int m = 1;
  for (int s = 0; s < 11; ++s) {
    __syncthreads();
#pragma unroll
    for (int it = 0; it < 4; ++it) {
      int t = (int)threadIdx.x + it * 256;
      int jm = t & ~(m - 1);
      float x0r = xr[t], x0i = xi[t];
      float x1r = xr[t + 1024], x1i = xi[t + 1024];
      float2 w = tw[jm];
      float sr = x0r + x1r, si = x0i + x1i;
      float dr = x0r - x1r, di = x0i - x1i;
      float pr = dr * w.x - di * w.y;
      float pi = dr * w.y + di * w.x;
      yr[t + jm] = sr;      yi[t + jm] = si;
      yr[t + jm + m] = pr;  yi[t + jm + m] = pi;
    }
    float* t0 = xr; xr = yr; yr = t0;
    float* t1 = xi; xi = yi; yi = t1;
    m <<= 1;
  }
  __syncthreads();
  *outr = xr; *outi = xi;
}

__global__ __launch_bounds__(256) void fwd_fft_kernel(const float* __restrict__ imp,
                                                      const float* __restrict__ winT,
                                                      const float2* __restrict__ twG,
                                                      float2* __restrict__ cur) {
  __shared__ float b0r[WINSZ], b0i[WINSZ], b1r[WINSZ], b1i[WINSZ];
  __shared__ float2 tw[HALFW];
  int wg = blockIdx.x;
  int b = wg >> 2, f = wg & 3;
  int tid = threadIdx.x;

  for (int i = tid; i < HALFW; i += 256) tw[i] = twG[i];
  for (int w = tid; w < WINSZ; w += 256) {
    int s = f * HALFW + w;
    float v = (s < IMPN) ? imp[(size_t)b * IMPN + s] * winT[w] : 0.0f;
    b0r[w] = v;
    b0i[w] = 0.0f;
  }
  float *rr, *ri;
  wg_fft2048(b0r, b0i, b1r, b1i, tw, &rr, &ri);
  for (int k = tid; k < NCOEF; k += 256)
    cur[(size_t)wg * NCOEF + k] = make_float2(rr[k], ri[k]);
}

// ---------------------------------------------------------------- recurrence checkpoints + tf transpose
__global__ __launch_bounds__(256) void recur_ck_t(const float* __restrict__ tf,
                                                  const float2* __restrict__ cur,
                                                  float2* __restrict__ ckp,
                                                  float* __restrict__ tft) {
  int id = blockIdx.x * 256 + threadIdx.x;
  if (id >= NB * NCOEF) return;
  int b = id / NCOEF;
  int k = id - b * NCOEF;

  float g = 3.14159265358979323846f * (float)k / 1024.0f;
  float sg, cg;
  sincosf(g, &sg, &cg);
  bool herm = (k == 0) || (k == HALFW);

  const float4* tf4 = (const float4*)(tf + (size_t)b * COLS + (size_t)k * NFR);
  const float2* curb = cur + (size_t)b * 4 * NCOEF + k;
  float* tftb = tft + (size_t)b * NFR * NCOEF + k;

  float pre = 0.0f, pim = 0.0f;
  for (int f4 = 0; f4 < 32; ++f4) {
    float4 tv = tf4[f4];
    float tfs[4] = {tv.x, tv.y, tv.z, tv.w};
#pragma unroll
    for (int u = 0; u < 4; ++u) {
      int f = 4 * f4 + u;
      tftb[(size_t)f * NCOEF] = tfs[u];       // coalesced transpose write
      if (f < 124) {
        float tfv = tfs[u];
        float cr = 0.0f, ci = 0.0f;
        if (f < 4) {
          float2 cv = curb[(size_t)f * NCOEF];
          cr = cv.x; ci = cv.y;
        }
        float ire = herm ? 0.0f : pim;
        float rre = fmaf(pre, cg, ire * sg);
        float rim = -fmaf(pre, sg, ire * cg);
        float sre = (cr + rre) * tfv;
        float sim = (ci + rim) * tfv;
        if ((f & 3) == 2)
          ckp[(size_t)((f - 2) >> 2) * NB * NCOEF + (size_t)b * NCOEF + k] = make_float2(sre, sim);
        pre = sre; pim = sim;
      }
    }
  }
}

// ---------------------------------------------------------------- fused recur + irfft + OLA
// Register DIF radix-4; P/Q planes; 2 LDS barriers/frame (beta removed:
// alpha's lgkmcnt(0)+barrier already retires all waves' prev stage-5 Q-reads).
// Wave-local stages ordered by compiler fences (in-order per-wave DS pipe).
__global__ __launch_bounds__(256) void fused_resyn(const float* __restrict__ tft,
                                                   const float2* __restrict__ cur,
                                                   const float2* __restrict__ ckp,
                                                   const float* __restrict__ winT,
                                                   const float2* __restrict__ twG,
                                                   float* __restrict__ out) {
  __shared__ f32x2 P[1024];   // X plane (mirror source)
  __shared__ f32x2 Q[1024];   // butterfly work plane

  int bidx = blockIdx.x;
  int b = bidx >> 5, c = bidx & 31;
  int t = threadIdx.x;

  // ---- recurrence slots: k = t + 256*i (i<4); thread 0 also owns k=1024
  float pre[5], pim[5], cgv[5], sgv[5];
#pragma unroll
  for (int i = 0; i < 5; ++i) {
    if (i == 4) { cgv[4] = -1.0f; sgv[4] = 0.0f; }
    else {
      float2 tv = twG[t + 256 * i];
      cgv[i] = tv.x; sgv[i] = -tv.y;       // cos/sin(pi*k/1024)
    }
    pre[i] = 0.0f; pim[i] = 0.0f;
  }
  if (c > 0) {
    const float2* ck = ckp + ((size_t)(c - 1) * NB + b) * NCOEF;
#pragma unroll
    for (int i = 0; i < 5; ++i) {
      if (i == 4 && t != 0) continue;
      int k = (i == 4) ? 1024 : t + 256 * i;
      float2 v = ck[k];
      pre[i] = v.x; pim[i] = v.y;
    }
  }

  // ---- base twiddles only (squares/cubes recomputed per frame, packed)
  float2 tl;
  tl = twG[2 * t];          f32x2 w1a = f32x2{tl.x, tl.y};
  tl = twG[8 * (t & 63)];   f32x2 w2a = f32x2{tl.x, tl.y};
  tl = twG[32 * (t & 15)];  f32x2 w3a = f32x2{tl.x, tl.y};
  tl = twG[128 * (t & 3)];  f32x2 w4a = f32x2{tl.x, tl.y};
  tl = twG[t];              f32x2 twp0 = f32x2{tl.x, tl.y};

  // ---- extract constants (digit-reversed positions); 1/2048 scale folded in
  const float Cs = 0.5f / 1024.0f;
  int mb = (t >> 6) + ((t >> 4) & 3) * 4 + ((t >> 2) & 3) * 16 + (t & 3) * 64;
  const float2* win2 = (const float2*)winT;
  f32x2 wv0, wv1, wv2, wv3;
  { float2 w = win2[mb];       wv0 = f32x2{w.x * Cs, w.y * Cs}; }
  { float2 w = win2[mb + 256]; wv1 = f32x2{w.x * Cs, w.y * Cs}; }
  { float2 w = win2[mb + 512]; wv2 = f32x2{w.x * Cs, w.y * Cs}; }
  { float2 w = win2[mb + 768]; wv3 = f32x2{w.x * Cs, w.y * Cs}; }

  // ---- LDS address constants (swizzled)
  int X0 = PHI(t);
  int B2 = 256 * (t >> 6) + ((t & 63) ^ (((t >> 4) & 3) << 2));
  int b3h = 64 * (t >> 4), i3 = t & 15;
  int b4h = 16 * (t >> 2), i4 = t & 3, c4 = (t >> 2) & 3;
  int p5 = b4h + 4 * ((t & 3) ^ c4);
  int pm0 = PHI((1024 - t) & 1023);
  int pm1 = PHI((1024 - (t + 256)) & 1023);
  int pm2 = PHI((1024 - (t + 512)) & 1023);
  int pm3 = PHI((1024 - (t + 768)) & 1023);

  const float* tftb = tft + (size_t)b * NFR * NCOEF;
  const float2* curb = cur + (size_t)b * 4 * NCOEF;

  int fs = (c == 0) ? 0 : 4 * c - 1;
  int fe = 4 * c + 3;
  f32x2 car0 = f32x2{0.0f, 0.0f}, car1 = f32x2{0.0f, 0.0f};

  // ---- tf prefetch for frame fs
  float ntf[5];
  {
    const float* tfr = tftb + (size_t)fs * NCOEF;
#pragma unroll
    for (int i = 0; i < 4; ++i) ntf[i] = tfr[t + 256 * i];
    ntf[4] = (t == 0) ? tfr[1024] : 0.0f;
  }

#define KEEP(x) asm volatile("" : "+v"(x))

  for (int f = fs; f <= fe; ++f) {
    // tie base twiddles so derived powers are recomputed (not hoisted)
    KEEP(w1a); KEEP(w2a); KEEP(w3a); KEEP(w4a); KEEP(twp0);

    float ctf[5];
#pragma unroll
    for (int i = 0; i < 5; ++i) ctf[i] = ntf[i];

    // ---- issue next frame's tf loads (hide under this frame's FFT)
    if (f < fe) {
      const float* tfr = tftb + (size_t)(f + 1) * NCOEF;
#pragma unroll
      for (int i = 0; i < 4; ++i) ntf[i] = tfr[t + 256 * i];
      ntf[4] = (t == 0) ? tfr[1024] : 0.0f;
    }

    // ---- advance recurrence (registers)
    float S[5], I[5];
#pragma unroll
    for (int i = 0; i < 5; ++i) {
      if (i == 4 && t != 0) { S[4] = 0.0f; I[4] = 0.0f; continue; }
      float cr = 0.0f, ci = 0.0f;
      if (f < 4) {
        int k = (i == 4) ? 1024 : t + 256 * i;
        float2 cv = curb[(size_t)f * NCOEF + k];
        cr = cv.x; ci = cv.y;
      }
      float rre = fmaf(pre[i], cgv[i], pim[i] * sgv[i]);
      float rim = -fmaf(pre[i], sgv[i], pim[i] * cgv[i]);
      S[i] = (cr + rre) * ctf[i];
      I[i] = (ci + rim) * ctf[i];
      pre[i] = S[i]; pim[i] = I[i];
    }

    // ---- X into P
#pragma unroll
    for (int i = 0; i < 4; ++i)
      P[X0 + 256 * i] = f32x2{S[i], I[i]};
    WGBAR();                               // (alpha) X visible; prev frame fully retired

    // ---- pack Z (own X from regs; mirror from P) + stage-1 butterfly (packed)
    const float R2 = 0.70710678118654752f;
    f32x2 twp1 = cmul2(twp0, f32x2{R2, -R2});
    f32x2 twp2 = f32x2{twp0.y, -twp0.x};
    f32x2 twp3 = f32x2{twp1.y, -twp1.x};
    f32x2 Z[4];
    {
      f32x2 xm[4];
      xm[0] = (t == 0) ? f32x2{S[4], 0.0f} : P[pm0];
      xm[1] = P[pm1]; xm[2] = P[pm2]; xm[3] = P[pm3];
      f32x2 twp[4] = {twp0, twp1, twp2, twp3};
#pragma unroll
      for (int i = 0; i < 4; ++i) {
        f32x2 x = f32x2{S[i], I[i]};
        f32x2 cjm = f32x2{xm[i].x, -xm[i].y};        // conj(mirror)
        f32x2 xe = x + cjm;
        f32x2 xp = x - cjm;
        f32x2 Xo = cmul2(xp, f32x2{twp[i].x, -twp[i].y});   // * e^{+2pi i j/2048}
        Z[i] = f32x2{xe.x - Xo.y, -(xe.y + Xo.x)};
      }
    }
    {
      f32x2 w1b = cmul2(w1a, w1a);
      f32x2 w1c = cmul2(w1b, w1a);
      f32x2 A = Z[0] + Z[2];
      f32x2 B = Z[0] - Z[2];
      f32x2 C = Z[1] + Z[3];
      f32x2 D = Z[1] - Z[3];
      f32x2 nD = nid(D);
      Q[X0]       = A + C;
      Q[X0 + 256] = cmul2(B + nD, w1a);
      Q[X0 + 512] = cmul2(A - C, w1b);
      Q[X0 + 768] = cmul2(B - nD, w1c);
    }
    WGBAR();                               // (gamma) y visible across waves

    // ---- stage 2 (wave-local, N=256)
    {
      f32x2 u0 = Q[B2], u1 = Q[B2 + 64], u2 = Q[B2 + 128], u3 = Q[B2 + 192];
      f32x2 w2b = cmul2(w2a, w2a);
      f32x2 w2c = cmul2(w2b, w2a);
      f32x2 A = u0 + u2, B = u0 - u2, C = u1 + u3, D = u1 - u3;
      f32x2 nD = nid(D);
      Q[B2]       = A + C;
      Q[B2 + 64]  = cmul2(B + nD, w2a);
      Q[B2 + 128] = cmul2(A - C, w2b);
      Q[B2 + 192] = cmul2(B - nD, w2c);
    }
    PIPEFENCE();

    // ---- stage 3 (N=64)
    {
      f32x2 u0 = Q[b3h + i3];
      f32x2 u1 = Q[b3h + 16 + (i3 ^ 4)];
      f32x2 u2 = Q[b3h + 32 + (i3 ^ 8)];
      f32x2 u3 = Q[b3h + 48 + (i3 ^ 12)];
      f32x2 w3b = cmul2(w3a, w3a);
      f32x2 w3c = cmul2(w3b, w3a);
      f32x2 A = u0 + u2, B = u0 - u2, C = u1 + u3, D = u1 - u3;
      f32x2 nD = nid(D);
      Q[b3h + i3]             = A + C;
      Q[b3h + 16 + (i3 ^ 4)]  = cmul2(B + nD, w3a);
      Q[b3h + 32 + (i3 ^ 8)]  = cmul2(A - C, w3b);
      Q[b3h + 48 + (i3 ^ 12)] = cmul2(B - nD, w3c);
    }
    PIPEFENCE();

    // ---- stage 4 (N=16)
    {
      f32x2 u0 = Q[b4h + 4 * (0 ^ c4) + i4];
      f32x2 u1 = Q[b4h + 4 * (1 ^ c4) + i4];
      f32x2 u2 = Q[b4h + 4 * (2 ^ c4) + i4];
      f32x2 u3 = Q[b4h + 4 * (3 ^ c4) + i4];
      f32x2 w4b = cmul2(w4a, w4a);
      f32x2 w4c = cmul2(w4b, w4a);
      f32x2 A = u0 + u2, B = u0 - u2, C = u1 + u3, D = u1 - u3;
      f32x2 nD = nid(D);
      Q[b4h + 4 * (0 ^ c4) + i4] = A + C;
      Q[b4h + 4 * (1 ^ c4) + i4] = cmul2(B + nD, w4a);
      Q[b4h + 4 * (2 ^ c4) + i4] = cmul2(A - C, w4b);
      Q[b4h + 4 * (3 ^ c4) + i4] = cmul2(B - nD, w4c);
    }
    PIPEFENCE();

    // ---- stage 5 (N=4, no twiddles) -> regs
    float4 q01 = *reinterpret_cast<const float4*>(&Q[p5]);
    float4 q23 = *reinterpret_cast<const float4*>(&Q[p5 + 2]);
    f32x2 z0, z1, z2, z3;
    {
      f32x2 a = f32x2{q01.x, q01.y}, bq = f32x2{q01.z, q01.w};
      f32x2 cq = f32x2{q23.x, q23.y}, d = f32x2{q23.z, q23.w};
      f32x2 A = a + cq, B = a - cq, C = bq + d, D = bq - d;
      f32x2 nD = nid(D);
      z0 = A + C;
      z1 = B + nD;
      z2 = A - C;
      z3 = B - nD;
    }

    // ---- extract: x[2m]=Re z[m]*wv.x, x[2m+1]=-Im z[m]*wv.y; m = mb + 256q
    f32x2 e0 = f32x2{z0.x, -z0.y} * wv0;
    f32x2 e1 = f32x2{z1.x, -z1.y} * wv1;
    f32x2 e2 = f32x2{z2.x, -z2.y} * wv2;
    f32x2 e3 = f32x2{z3.x, -z3.y} * wv3;
    if (f >= 4 * c) {
      f32x2* ob2 = (f32x2*)(out + (size_t)b * NSAMP + (size_t)f * 1024);
      ob2[mb]       = e0 + car0;
      ob2[mb + 256] = e1 + car1;
    }
    car0 = e2;
    car1 = e3;
  }
#undef KEEP
}

// ---------------------------------------------------------------- launch
extern "C" void kernel_launch(void* const* d_in, const int* in_sizes, int n_in,
                              void* d_out, int out_size, void* d_ws, size_t ws_size,
                              hipStream_t stream) {
  const float* z    = (const float*)d_in[0];
  const float* imp  = (const float*)d_in[1];
  const float* W    = (const float*)d_in[2];
  const float* bias = (const float*)d_in[3];

  float* ws = (float*)d_ws;
  float*  tf   = ws + TF_OFF;
  float*  tft  = ws + TFT_OFF;
  float2* cur  = (float2*)(ws + CUR_OFF);
  float2* ckp  = (float2*)(ws + CK_OFF);
  float*  winT = ws + WINT_OFF;
  float2* twG  = (float2*)(ws + TW_OFF);
  short*  zbf  = (short*)(ws + ZBF_OFF);
  float*  out  = (float*)d_out;

  init_tables<<<32, 256, 0, stream>>>(z, winT, twG, zbf);
  tf_gemm_mfma<<<COLS / 32, 256, 0, stream>>>(zbf, W, bias, tf);
  fwd_fft_kernel<<<NB * 4, 256, 0, stream>>>(imp, winT, twG, cur);
  recur_ck_t<<<(NB * NCOEF + 255) / 256, 256, 0, stream>>>(tf, cur, ckp, tft);
  fused_resyn<<<NB * NCHUNK, 256, 0, stream>>>(tft, cur, ckp, winT, twG, out);
}